// Round 1
// baseline (5339.246 us; speedup 1.0000x reference)
//
#include <hip/hip_runtime.h>
#include <hip/hip_bf16.h>

typedef __attribute__((ext_vector_type(4))) float f4v;
typedef __attribute__((ext_vector_type(4))) short s4v;
typedef __attribute__((ext_vector_type(8))) short s8v;

#define DEVINL __device__ __forceinline__

DEVINL short f2bf(float f) {
  unsigned u = __float_as_uint(f);
  u += 0x7FFFu + ((u >> 16) & 1u);
  return (short)(u >> 16);
}
DEVINL float sigm(float x) { return 1.f / (1.f + expf(-x)); }

// ---------------- init recurrent states (every call: harness replays graph) --
__global__ __launch_bounds__(256) void k_init(const float* __restrict__ enc_h,
                                              const float* __restrict__ enc_c,
                                              float* __restrict__ h0, float* __restrict__ h1,
                                              float* __restrict__ c0, float* __restrict__ c1) {
  int i = blockIdx.x * 256 + threadIdx.x;  // 0..16383 (32*512)
  h0[i] = enc_h[i];
  h1[i] = enc_h[16384 + i];
  c0[i] = enc_c[i];
  c1[i] = enc_c[16384 + i];
}

// ---------------- w_enc[j] = sum_k attn2_w[k] * attn1_w[k*2048 + j], j<1024 --
__global__ __launch_bounds__(256) void k_weff(const float* __restrict__ attn1_w,
                                              const float* __restrict__ attn2_w,
                                              float* __restrict__ w_enc) {
  __shared__ float part[8][32];
  int t = threadIdx.x;
  int jl = t & 31, kp = t >> 5;
  int j = blockIdx.x * 32 + jl;
  float acc = 0.f;
  for (int k = kp * 256; k < kp * 256 + 256; ++k)
    acc += attn2_w[k] * attn1_w[(long)k * 2048 + j];
  part[kp][jl] = acc;
  __syncthreads();
  if (t < 32) {
    float s = 0.f;
    for (int p = 0; p < 8; ++p) s += part[p][t];
    w_enc[blockIdx.x * 32 + t] = s;
  }
}

// ---------------- per-b: logits -> softmax -> ctx[b, 0:1024] ----------------
__global__ __launch_bounds__(256) void k_attn(const float* __restrict__ enc,
                                              const float* __restrict__ w_enc,
                                              float* __restrict__ ctx) {
  __shared__ float red[256];
  __shared__ float wls[128];
  int b = blockIdx.x, t = threadIdx.x;
  int s = t >> 1, half = t & 1;
  const float* e = enc + ((long)b * 128 + s) * 1024 + half * 512;
  const float* wv = w_enc + half * 512;
  float acc = 0.f;
  for (int k = 0; k < 512; k += 4) {
    f4v ev = *(const f4v*)(e + k);
    f4v w4 = *(const f4v*)(wv + k);
    acc += ev[0] * w4[0] + ev[1] * w4[1] + ev[2] * w4[2] + ev[3] * w4[3];
  }
  red[t] = acc;
  __syncthreads();
  if (half == 0) wls[s] = red[t] + red[t + 1];
  __syncthreads();
  // max reduce over 128
  red[t] = (t < 128) ? wls[t] : -3.4e38f;
  __syncthreads();
  for (int off = 128; off >= 1; off >>= 1) {
    if (t < off) red[t] = fmaxf(red[t], red[t + off]);
    __syncthreads();
  }
  float mx = red[0];
  __syncthreads();
  if (t < 128) { float ex = expf(wls[t] - mx); wls[t] = ex; red[t] = ex; }
  else red[t] = 0.f;
  __syncthreads();
  for (int off = 128; off >= 1; off >>= 1) {
    if (t < off) red[t] += red[t + off];
    __syncthreads();
  }
  float inv = 1.f / red[0];
  __syncthreads();
  if (t < 128) wls[t] *= inv;
  __syncthreads();
  // ctx: 4 dims per thread
  float a0 = 0.f, a1 = 0.f, a2 = 0.f, a3 = 0.f;
  for (int ss = 0; ss < 128; ++ss) {
    float w = wls[ss];
    const float* er = enc + ((long)b * 128 + ss) * 1024;
    a0 += w * er[t];
    a1 += w * er[t + 256];
    a2 += w * er[t + 512];
    a3 += w * er[t + 768];
  }
  ctx[b * 1024 + t] = a0;
  ctx[b * 1024 + t + 256] = a1;
  ctx[b * 1024 + t + 512] = a2;
  ctx[b * 1024 + t + 768] = a3;
}

// -------- ctxpre[b][j] = ctx[b] . w_ih0[j, 512:1536] + b_ih0[j] + b_hh0[j] ---
__global__ __launch_bounds__(256) void k_ctxpre(const float* __restrict__ w_ih0,
                                                const float* __restrict__ b_ih0,
                                                const float* __restrict__ b_hh0,
                                                const float* __restrict__ ctx,
                                                float* __restrict__ ctxpre) {
  int t = threadIdx.x;
  int j = blockIdx.x * 8 + (t >> 5);
  int b = t & 31;
  float acc = b_ih0[j] + b_hh0[j];
  const float* w = w_ih0 + (long)j * 1536 + 512;
  const float* c = ctx + b * 1024;
  for (int k = 0; k < 1024; k += 4) {
    f4v wv = *(const f4v*)(w + k);
    f4v cv = *(const f4v*)(c + k);
    acc += wv[0] * cv[0] + wv[1] * cv[1] + wv[2] * cv[2] + wv[3] * cv[3];
  }
  ctxpre[b * 2048 + j] = acc;
}

// ---------------- generic bf16 MFMA GEMM:  C[m][n] = A[m,:].B[n,:] (+bias) ---
// A fp32 [M x lda] (optionally row-indirected via a_rows), B fp32 [N x ldb],
// converted to bf16 during LDS staging. 128x128 tile, BK=64, 4 waves (2x2).
__global__ __launch_bounds__(256) void gemm_bf16_nt(
    const float* __restrict__ A, const float* __restrict__ B,
    const int* __restrict__ a_rows, const float* __restrict__ bias,
    float* __restrict__ C, int K, int lda, int ldb, int ldc) {
  __shared__ short As[128 * 72];
  __shared__ short Bs[128 * 72];
  int n0 = blockIdx.x * 128, m0 = blockIdx.y * 128;
  int t = threadIdx.x;
  int lane = t & 63, w = t >> 6;
  int wm = w & 1, wn = w >> 1;
  f4v acc[4][4];
#pragma unroll
  for (int mi = 0; mi < 4; ++mi)
#pragma unroll
    for (int ni = 0; ni < 4; ++ni) acc[mi][ni] = (f4v){0.f, 0.f, 0.f, 0.f};

  int sr = t >> 1;            // staging row 0..127
  int sh = (t & 1) * 32;      // staging col group (floats)
  long arow = a_rows ? (long)a_rows[m0 + sr] : (long)(m0 + sr);
  const float* ap = A + arow * lda + sh;
  const float* bp = B + (long)(n0 + sr) * ldb + sh;
  short* as = &As[sr * 72 + sh];
  short* bs = &Bs[sr * 72 + sh];

  for (int k0 = 0; k0 < K; k0 += 64) {
#pragma unroll
    for (int i = 0; i < 8; ++i) {
      f4v va = *(const f4v*)(ap + k0 + i * 4);
      f4v vb = *(const f4v*)(bp + k0 + i * 4);
      s4v sa, sb;
      sa[0] = f2bf(va[0]); sa[1] = f2bf(va[1]); sa[2] = f2bf(va[2]); sa[3] = f2bf(va[3]);
      sb[0] = f2bf(vb[0]); sb[1] = f2bf(vb[1]); sb[2] = f2bf(vb[2]); sb[3] = f2bf(vb[3]);
      *(s4v*)(as + i * 4) = sa;
      *(s4v*)(bs + i * 4) = sb;
    }
    __syncthreads();
#pragma unroll
    for (int ks = 0; ks < 2; ++ks) {
      s8v af[4], bf[4];
#pragma unroll
      for (int mi = 0; mi < 4; ++mi)
        af[mi] = *(const s8v*)&As[(wm * 64 + mi * 16 + (lane & 15)) * 72 + ks * 32 + (lane >> 4) * 8];
#pragma unroll
      for (int ni = 0; ni < 4; ++ni)
        bf[ni] = *(const s8v*)&Bs[(wn * 64 + ni * 16 + (lane & 15)) * 72 + ks * 32 + (lane >> 4) * 8];
#pragma unroll
      for (int mi = 0; mi < 4; ++mi)
#pragma unroll
        for (int ni = 0; ni < 4; ++ni)
          acc[mi][ni] = __builtin_amdgcn_mfma_f32_16x16x32_bf16(af[mi], bf[ni], acc[mi][ni], 0, 0, 0);
    }
    __syncthreads();
  }
  int fq = lane >> 4, fr = lane & 15;
#pragma unroll
  for (int mi = 0; mi < 4; ++mi)
#pragma unroll
    for (int ni = 0; ni < 4; ++ni) {
      long col = n0 + wn * 64 + ni * 16 + fr;
      float bv = bias ? bias[col] : 0.f;
      long rowb = m0 + wm * 64 + mi * 16 + fq * 4;
#pragma unroll
      for (int r = 0; r < 4; ++r)
        C[(rowb + r) * (long)ldc + col] = acc[mi][ni][r] + bv;
    }
}

// ---------------- LSTM layer 0 step: block owns 4 h-dims, all gates, all b ---
__global__ __launch_bounds__(256) void lstm_l0(
    const float* __restrict__ h_prev, float* __restrict__ h_next,
    float* __restrict__ c_state, const float* __restrict__ w_hh,
    const float* __restrict__ embpre, const float* __restrict__ ctxpre, int tstep) {
  __shared__ float g_lds[512];
  int t = threadIdx.x;
  int b = t & 31, gate = (t >> 5) & 3, hlo = t >> 7;  // hlo in {0,1}
  int hbase = blockIdx.x * 4;
  int jA = gate * 512 + hbase + hlo;
  int jB = jA + 2;
  float accA = 0.f, accB = 0.f;
  const float* wA = w_hh + (long)jA * 512;
  const float* wB = w_hh + (long)jB * 512;
  const float* hp = h_prev + b * 512;
  for (int k = 0; k < 512; k += 4) {
    f4v hv = *(const f4v*)(hp + k);
    f4v wa = *(const f4v*)(wA + k);
    f4v wb = *(const f4v*)(wB + k);
    accA += hv[0] * wa[0] + hv[1] * wa[1] + hv[2] * wa[2] + hv[3] * wa[3];
    accB += hv[0] * wb[0] + hv[1] * wb[1] + hv[2] * wb[2] + hv[3] * wb[3];
  }
  long m = (long)b * 64 + tstep;
  accA += embpre[m * 2048 + jA] + ctxpre[b * 2048 + jA];
  accB += embpre[m * 2048 + jB] + ctxpre[b * 2048 + jB];
  g_lds[hlo * 128 + gate * 32 + b] = accA;
  g_lds[(hlo + 2) * 128 + gate * 32 + b] = accB;
  __syncthreads();
  if (t < 128) {
    int hh = t >> 5, bb = t & 31;
    float gi = g_lds[hh * 128 + 0 + bb];
    float gf = g_lds[hh * 128 + 32 + bb];
    float gg = g_lds[hh * 128 + 64 + bb];
    float go = g_lds[hh * 128 + 96 + bb];
    int h = hbase + hh;
    float c = c_state[bb * 512 + h];
    float cn = sigm(gf) * c + sigm(gi) * tanhf(gg);
    float hn = sigm(go) * tanhf(cn);
    c_state[bb * 512 + h] = cn;
    h_next[bb * 512 + h] = hn;
  }
}

// ---------------- LSTM layer 1 step (x = new h0; also emits h1seq) -----------
__global__ __launch_bounds__(256) void lstm_l1(
    const float* __restrict__ x, const float* __restrict__ h_prev,
    float* __restrict__ h_next, float* __restrict__ c_state,
    const float* __restrict__ w_ih, const float* __restrict__ w_hh,
    const float* __restrict__ b_ih, const float* __restrict__ b_hh,
    float* __restrict__ h1seq, int tstep) {
  __shared__ float g_lds[512];
  int t = threadIdx.x;
  int b = t & 31, gate = (t >> 5) & 3, hlo = t >> 7;
  int hbase = blockIdx.x * 4;
  int jA = gate * 512 + hbase + hlo;
  int jB = jA + 2;
  float accA = b_ih[jA] + b_hh[jA];
  float accB = b_ih[jB] + b_hh[jB];
  const float* wiA = w_ih + (long)jA * 512;
  const float* wiB = w_ih + (long)jB * 512;
  const float* whA = w_hh + (long)jA * 512;
  const float* whB = w_hh + (long)jB * 512;
  const float* xb = x + b * 512;
  const float* hb = h_prev + b * 512;
  for (int k = 0; k < 512; k += 4) {
    f4v xv = *(const f4v*)(xb + k);
    f4v hv = *(const f4v*)(hb + k);
    f4v wa = *(const f4v*)(wiA + k);
    f4v wb = *(const f4v*)(wiB + k);
    f4v va = *(const f4v*)(whA + k);
    f4v vb = *(const f4v*)(whB + k);
    accA += xv[0] * wa[0] + xv[1] * wa[1] + xv[2] * wa[2] + xv[3] * wa[3];
    accB += xv[0] * wb[0] + xv[1] * wb[1] + xv[2] * wb[2] + xv[3] * wb[3];
    accA += hv[0] * va[0] + hv[1] * va[1] + hv[2] * va[2] + hv[3] * va[3];
    accB += hv[0] * vb[0] + hv[1] * vb[1] + hv[2] * vb[2] + hv[3] * vb[3];
  }
  g_lds[hlo * 128 + gate * 32 + b] = accA;
  g_lds[(hlo + 2) * 128 + gate * 32 + b] = accB;
  __syncthreads();
  if (t < 128) {
    int hh = t >> 5, bb = t & 31;
    float gi = g_lds[hh * 128 + 0 + bb];
    float gf = g_lds[hh * 128 + 32 + bb];
    float gg = g_lds[hh * 128 + 64 + bb];
    float go = g_lds[hh * 128 + 96 + bb];
    int h = hbase + hh;
    float c = c_state[bb * 512 + h];
    float cn = sigm(gf) * c + sigm(gi) * tanhf(gg);
    float hn = sigm(go) * tanhf(cn);
    c_state[bb * 512 + h] = cn;
    h_next[bb * 512 + h] = hn;
    h1seq[((long)bb * 64 + tstep) * 512 + h] = hn;
  }
}

extern "C" void kernel_launch(void* const* d_in, const int* in_sizes, int n_in,
                              void* d_out, int out_size, void* d_ws, size_t ws_size,
                              hipStream_t stream) {
  const int*   tokens  = (const int*)  d_in[0];
  const float* enc_out = (const float*)d_in[1];
  const float* enc_h   = (const float*)d_in[2];
  const float* enc_c   = (const float*)d_in[3];
  const float* emb     = (const float*)d_in[4];
  const float* attn1_w = (const float*)d_in[5];
  const float* attn2_w = (const float*)d_in[7];
  const float* w_ih0   = (const float*)d_in[9];
  const float* w_hh0   = (const float*)d_in[10];
  const float* b_ih0   = (const float*)d_in[11];
  const float* b_hh0   = (const float*)d_in[12];
  const float* w_ih1   = (const float*)d_in[13];
  const float* w_hh1   = (const float*)d_in[14];
  const float* b_ih1   = (const float*)d_in[15];
  const float* b_hh1   = (const float*)d_in[16];
  const float* out_w   = (const float*)d_in[17];
  const float* out_b   = (const float*)d_in[18];
  float* out = (float*)d_out;

  float* f = (float*)d_ws;
  float* w_enc  = f;                 // 1024
  float* ctx    = f + 1024;          // 32*1024
  float* ctxpre = f + 33792;         // 32*2048
  float* embpre = f + 99328;         // 2048*2048
  float* h0a    = f + 4293632;       // 32*512
  float* h0b    = f + 4310016;
  float* h1a    = f + 4326400;
  float* h1b    = f + 4342784;
  float* c0     = f + 4359168;
  float* c1     = f + 4375552;
  float* h1seq  = f + 4391936;       // 2048*512

  k_init<<<64, 256, 0, stream>>>(enc_h, enc_c, h0a, h1a, c0, c1);
  k_weff<<<32, 256, 0, stream>>>(attn1_w, attn2_w, w_enc);
  k_attn<<<32, 256, 0, stream>>>(enc_out, w_enc, ctx);
  k_ctxpre<<<256, 256, 0, stream>>>(w_ih0, b_ih0, b_hh0, ctx, ctxpre);
  // embpre[m][j] = emb[tokens[m]] . w_ih0[j, 0:512]
  gemm_bf16_nt<<<dim3(16, 16), 256, 0, stream>>>(emb, w_ih0, tokens, nullptr, embpre,
                                                 512, 512, 1536, 2048);
  for (int tstep = 0; tstep < 64; ++tstep) {
    const float* h0r = (tstep & 1) ? h0b : h0a;
    float*       h0w = (tstep & 1) ? h0a : h0b;
    const float* h1r = (tstep & 1) ? h1b : h1a;
    float*       h1w = (tstep & 1) ? h1a : h1b;
    lstm_l0<<<128, 256, 0, stream>>>(h0r, h0w, c0, w_hh0, embpre, ctxpre, tstep);
    lstm_l1<<<128, 256, 0, stream>>>(h0w, h1r, h1w, c1, w_ih1, w_hh1, b_ih1, b_hh1,
                                     h1seq, tstep);
  }
  // out[m][v] = h1seq[m] . out_w[v] + out_b[v]
  gemm_bf16_nt<<<dim3(250, 16), 256, 0, stream>>>(h1seq, out_w, nullptr, out_b, out,
                                                  512, 512, 512, 32000);
}

// Round 2
// 2227.360 us; speedup vs baseline: 2.3971x; 2.3971x over previous
//
#include <hip/hip_runtime.h>
#include <hip/hip_bf16.h>

typedef __attribute__((ext_vector_type(4))) float f4v;
typedef __attribute__((ext_vector_type(4))) short s4v;
typedef __attribute__((ext_vector_type(8))) short s8v;

#define DEVINL __device__ __forceinline__
#define NBLK 128
#define PADK 536          // 512 + 24 shorts: 1072B row stride = 67 dwords -> 2-way max on b128
#define WROWS (16 * PADK) // shorts per weight slice

DEVINL short f2bf(float f) {
  unsigned u = __float_as_uint(f);
  u += 0x7FFFu + ((u >> 16) & 1u);
  return (short)(u >> 16);
}
DEVINL float bf2f(short s) {
  return __uint_as_float(((unsigned)(unsigned short)s) << 16);
}
DEVINL float sigm(float x) { return 1.f / (1.f + expf(-x)); }

DEVINL void gridbar(unsigned* bar, unsigned* phase) {
  __syncthreads();
  if (threadIdx.x == 0) {
    __threadfence();
    ++*phase;
    __hip_atomic_fetch_add(bar, 1u, __ATOMIC_RELAXED, __HIP_MEMORY_SCOPE_AGENT);
    unsigned target = *phase * (unsigned)NBLK;
    while (__hip_atomic_load(bar, __ATOMIC_RELAXED, __HIP_MEMORY_SCOPE_AGENT) < target)
      __builtin_amdgcn_s_sleep(1);
    __threadfence();
  }
  __syncthreads();
}

// ---------------- init: h buffers (bf16 hi/lo, parity 0) + barrier ----------
__global__ __launch_bounds__(256) void k_init2(const float* __restrict__ enc_h,
                                               short* __restrict__ hbuf,
                                               unsigned* __restrict__ bar) {
  int i = blockIdx.x * 256 + threadIdx.x;  // 0..16383
  float h0 = enc_h[i], h1 = enc_h[16384 + i];
  short h0h = f2bf(h0), h1h = f2bf(h1);
  hbuf[i] = h0h;
  hbuf[32768 + i] = f2bf(h0 - bf2f(h0h));
  hbuf[65536 + i] = h1h;
  hbuf[98304 + i] = f2bf(h1 - bf2f(h1h));
  if (i == 0) *bar = 0u;
}

// ---------------- w_enc[j] = sum_k attn2_w[k] * attn1_w[k*2048 + j], j<1024 --
__global__ __launch_bounds__(256) void k_weff(const float* __restrict__ attn1_w,
                                              const float* __restrict__ attn2_w,
                                              float* __restrict__ w_enc) {
  __shared__ float part[8][32];
  int t = threadIdx.x;
  int jl = t & 31, kp = t >> 5;
  int j = blockIdx.x * 32 + jl;
  float acc = 0.f;
  for (int k = kp * 256; k < kp * 256 + 256; ++k)
    acc += attn2_w[k] * attn1_w[(long)k * 2048 + j];
  part[kp][jl] = acc;
  __syncthreads();
  if (t < 32) {
    float s = 0.f;
    for (int p = 0; p < 8; ++p) s += part[p][t];
    w_enc[blockIdx.x * 32 + t] = s;
  }
}

// ---------------- per-b: logits -> softmax -> ctx[b, 0:1024] ----------------
__global__ __launch_bounds__(256) void k_attn(const float* __restrict__ enc,
                                              const float* __restrict__ w_enc,
                                              float* __restrict__ ctx) {
  __shared__ float red[256];
  __shared__ float wls[128];
  int b = blockIdx.x, t = threadIdx.x;
  int s = t >> 1, half = t & 1;
  const float* e = enc + ((long)b * 128 + s) * 1024 + half * 512;
  const float* wv = w_enc + half * 512;
  float acc = 0.f;
  for (int k = 0; k < 512; k += 4) {
    f4v ev = *(const f4v*)(e + k);
    f4v w4 = *(const f4v*)(wv + k);
    acc += ev[0] * w4[0] + ev[1] * w4[1] + ev[2] * w4[2] + ev[3] * w4[3];
  }
  red[t] = acc;
  __syncthreads();
  if (half == 0) wls[s] = red[t] + red[t + 1];
  __syncthreads();
  red[t] = (t < 128) ? wls[t] : -3.4e38f;
  __syncthreads();
  for (int off = 128; off >= 1; off >>= 1) {
    if (t < off) red[t] = fmaxf(red[t], red[t + off]);
    __syncthreads();
  }
  float mx = red[0];
  __syncthreads();
  if (t < 128) { float ex = expf(wls[t] - mx); wls[t] = ex; red[t] = ex; }
  else red[t] = 0.f;
  __syncthreads();
  for (int off = 128; off >= 1; off >>= 1) {
    if (t < off) red[t] += red[t + off];
    __syncthreads();
  }
  float inv = 1.f / red[0];
  __syncthreads();
  if (t < 128) wls[t] *= inv;
  __syncthreads();
  float a0 = 0.f, a1 = 0.f, a2 = 0.f, a3 = 0.f;
  for (int ss = 0; ss < 128; ++ss) {
    float w = wls[ss];
    const float* er = enc + ((long)b * 128 + ss) * 1024;
    a0 += w * er[t];
    a1 += w * er[t + 256];
    a2 += w * er[t + 512];
    a3 += w * er[t + 768];
  }
  ctx[b * 1024 + t] = a0;
  ctx[b * 1024 + t + 256] = a1;
  ctx[b * 1024 + t + 512] = a2;
  ctx[b * 1024 + t + 768] = a3;
}

// -------- ctxpre[b][j] = ctx[b] . w_ih0[j, 512:1536] + b_ih0[j] + b_hh0[j] ---
__global__ __launch_bounds__(256) void k_ctxpre(const float* __restrict__ w_ih0,
                                                const float* __restrict__ b_ih0,
                                                const float* __restrict__ b_hh0,
                                                const float* __restrict__ ctx,
                                                float* __restrict__ ctxpre) {
  int t = threadIdx.x;
  int j = blockIdx.x * 8 + (t >> 5);
  int b = t & 31;
  float acc = b_ih0[j] + b_hh0[j];
  const float* w = w_ih0 + (long)j * 1536 + 512;
  const float* c = ctx + b * 1024;
  for (int k = 0; k < 1024; k += 4) {
    f4v wv = *(const f4v*)(w + k);
    f4v cv = *(const f4v*)(c + k);
    acc += wv[0] * cv[0] + wv[1] * cv[1] + wv[2] * cv[2] + wv[3] * cv[3];
  }
  ctxpre[b * 2048 + j] = acc;
}

// ---------------- generic bf16 MFMA GEMM:  C[m][n] = A[m,:].B[n,:] (+bias) ---
template <bool NT>
__global__ __launch_bounds__(256) void gemm_bf16_nt(
    const float* __restrict__ A, const float* __restrict__ B,
    const int* __restrict__ a_rows, const float* __restrict__ bias,
    float* __restrict__ C, int K, int lda, int ldb, int ldc) {
  __shared__ short As[128 * 72];
  __shared__ short Bs[128 * 72];
  int n0 = blockIdx.x * 128, m0 = blockIdx.y * 128;
  int t = threadIdx.x;
  int lane = t & 63, w = t >> 6;
  int wm = w & 1, wn = w >> 1;
  f4v acc[4][4];
#pragma unroll
  for (int mi = 0; mi < 4; ++mi)
#pragma unroll
    for (int ni = 0; ni < 4; ++ni) acc[mi][ni] = (f4v){0.f, 0.f, 0.f, 0.f};

  int sr = t >> 1;
  int sh = (t & 1) * 32;
  long arow = a_rows ? (long)a_rows[m0 + sr] : (long)(m0 + sr);
  const float* ap = A + arow * lda + sh;
  const float* bp = B + (long)(n0 + sr) * ldb + sh;
  short* as = &As[sr * 72 + sh];
  short* bs = &Bs[sr * 72 + sh];

  for (int k0 = 0; k0 < K; k0 += 64) {
#pragma unroll
    for (int i = 0; i < 8; ++i) {
      f4v va = *(const f4v*)(ap + k0 + i * 4);
      f4v vb = *(const f4v*)(bp + k0 + i * 4);
      s4v sa, sb;
      sa[0] = f2bf(va[0]); sa[1] = f2bf(va[1]); sa[2] = f2bf(va[2]); sa[3] = f2bf(va[3]);
      sb[0] = f2bf(vb[0]); sb[1] = f2bf(vb[1]); sb[2] = f2bf(vb[2]); sb[3] = f2bf(vb[3]);
      *(s4v*)(as + i * 4) = sa;
      *(s4v*)(bs + i * 4) = sb;
    }
    __syncthreads();
#pragma unroll
    for (int ks = 0; ks < 2; ++ks) {
      s8v af[4], bf[4];
#pragma unroll
      for (int mi = 0; mi < 4; ++mi)
        af[mi] = *(const s8v*)&As[(wm * 64 + mi * 16 + (lane & 15)) * 72 + ks * 32 + (lane >> 4) * 8];
#pragma unroll
      for (int ni = 0; ni < 4; ++ni)
        bf[ni] = *(const s8v*)&Bs[(wn * 64 + ni * 16 + (lane & 15)) * 72 + ks * 32 + (lane >> 4) * 8];
#pragma unroll
      for (int mi = 0; mi < 4; ++mi)
#pragma unroll
        for (int ni = 0; ni < 4; ++ni)
          acc[mi][ni] = __builtin_amdgcn_mfma_f32_16x16x32_bf16(af[mi], bf[ni], acc[mi][ni], 0, 0, 0);
    }
    __syncthreads();
  }
  int fq = lane >> 4, fr = lane & 15;
#pragma unroll
  for (int mi = 0; mi < 4; ++mi)
#pragma unroll
    for (int ni = 0; ni < 4; ++ni) {
      long col = n0 + wn * 64 + ni * 16 + fr;
      float bv = bias ? bias[col] : 0.f;
      long rowb = m0 + wm * 64 + mi * 16 + fq * 4;
#pragma unroll
      for (int r = 0; r < 4; ++r) {
        float val = acc[mi][ni][r] + bv;
        float* cp = &C[(rowb + r) * (long)ldc + col];
        if (NT) __builtin_nontemporal_store(val, cp);
        else *cp = val;
      }
    }
}

// ---------------- persistent 2-layer LSTM recurrence (64 steps) -------------
// 128 blocks x 256 threads. Block bz owns h-dims [bz*4, bz*4+4) of BOTH layers.
// Weight slices LDS-resident as bf16 hi/lo; c-state in registers; h ping-pongs
// through global bf16 hi/lo buffers with 2 grid barriers per step.
__global__ __launch_bounds__(256, 1) void lstm_persist(
    const float* __restrict__ w_hh0, const float* __restrict__ w_ih1,
    const float* __restrict__ w_hh1,
    const float* __restrict__ b_ih1, const float* __restrict__ b_hh1,
    const float* __restrict__ enc_c,
    const float* __restrict__ embpre, const float* __restrict__ ctxpre,
    short* __restrict__ hbuf, float* __restrict__ h1seq,
    unsigned* __restrict__ bar) {
  __shared__ alignas(16) short wlds[6 * WROWS];  // w0h,w0l,w1ih,w1il,w1hh,w1hl
  __shared__ float ctxp_l[32][16];
  __shared__ float bias1_l[16];
  __shared__ float gbuf[2][32][17];

  const int tid = threadIdx.x;
  const int hb4 = blockIdx.x * 4;
  const int lane = tid & 63, wid = tid >> 6;
  const int mt = wid & 1, kh = wid >> 1;
  const int fr = lane & 15, fq = lane >> 4;

  // stage weight slices: rows c=0..15 ordered c = gate*4 + hlocal
  for (int base = tid * 4; base < 48 * 512; base += 1024) {
    int row = base >> 9, k = base & 511;
    int m = row >> 4, c = row & 15;
    int j = ((c >> 2) << 9) + hb4 + (c & 3);
    const float* wsrc = (m == 0) ? w_hh0 : ((m == 1) ? w_ih1 : w_hh1);
    f4v v = *(const f4v*)(wsrc + (long)j * 512 + k);
    short* hi = &wlds[(m * 2) * WROWS + c * PADK + k];
    short* lo = &wlds[(m * 2 + 1) * WROWS + c * PADK + k];
#pragma unroll
    for (int e = 0; e < 4; ++e) {
      short hh = f2bf(v[e]);
      hi[e] = hh;
      lo[e] = f2bf(v[e] - bf2f(hh));
    }
  }
  for (int i = tid; i < 512; i += 256) {
    int b = i >> 4, c = i & 15;
    ctxp_l[b][c] = ctxpre[b * 2048 + ((c >> 2) << 9) + hb4 + (c & 3)];
  }
  if (tid < 16) {
    int j = ((tid >> 2) << 9) + hb4 + (tid & 3);
    bias1_l[tid] = b_ih1[j] + b_hh1[j];
  }
  const int cb = tid & 31, chl = (tid >> 5) & 3;
  float c0r = 0.f, c1r = 0.f;
  if (tid < 128) {
    c0r = enc_c[cb * 512 + hb4 + chl];
    c1r = enc_c[16384 + cb * 512 + hb4 + chl];
  }
  __syncthreads();

  short* H0H[2] = {hbuf, hbuf + 16384};
  short* H0L[2] = {hbuf + 32768, hbuf + 49152};
  short* H1H[2] = {hbuf + 65536, hbuf + 81920};
  short* H1L[2] = {hbuf + 98304, hbuf + 114688};
  unsigned phase = 0;
  const int foff = (mt * 16 + fr) * 512 + kh * 256 + fq * 8;
  const int woff = fr * PADK + kh * 256 + fq * 8;

  for (int t = 0; t < 64; ++t) {
    int rp = t & 1, wp = rp ^ 1;
    // prefetch embpre additions for cell0 (hide latency under MFMA)
    float e4[4] = {0.f, 0.f, 0.f, 0.f};
    if (tid < 128) {
      const float* ep = embpre + ((long)cb * 64 + t) * 2048 + hb4 + chl;
#pragma unroll
      for (int g = 0; g < 4; ++g) e4[g] = ep[g << 9];
    }
    // ---------- layer 0: gates = h0[rp] @ w_hh0_slice^T ----------
    {
      f4v a_hh = {0.f, 0.f, 0.f, 0.f}, a_hl = a_hh, a_lh = a_hh;
      const short* ah = H0H[rp] + foff;
      const short* al = H0L[rp] + foff;
      const short* bh = &wlds[0 * WROWS + woff];
      const short* bl = &wlds[1 * WROWS + woff];
#pragma unroll
      for (int ks = 0; ks < 8; ++ks) {
        s8v Ah = *(const s8v*)(ah + ks * 32);
        s8v Al = *(const s8v*)(al + ks * 32);
        s8v Bh = *(const s8v*)(bh + ks * 32);
        s8v Bl = *(const s8v*)(bl + ks * 32);
        a_hh = __builtin_amdgcn_mfma_f32_16x16x32_bf16(Ah, Bh, a_hh, 0, 0, 0);
        a_hl = __builtin_amdgcn_mfma_f32_16x16x32_bf16(Ah, Bl, a_hl, 0, 0, 0);
        a_lh = __builtin_amdgcn_mfma_f32_16x16x32_bf16(Al, Bh, a_lh, 0, 0, 0);
      }
      f4v acc = a_hh + a_hl + a_lh;
#pragma unroll
      for (int r = 0; r < 4; ++r) gbuf[kh][mt * 16 + fq * 4 + r][fr] = acc[r];
    }
    __syncthreads();
    if (tid < 128) {
      float g4[4];
#pragma unroll
      for (int g = 0; g < 4; ++g) {
        int c = g * 4 + chl;
        g4[g] = gbuf[0][cb][c] + gbuf[1][cb][c] + ctxp_l[cb][c] + e4[g];
      }
      float cn = sigm(g4[1]) * c0r + sigm(g4[0]) * tanhf(g4[2]);
      float hn = sigm(g4[3]) * tanhf(cn);
      c0r = cn;
      short hh = f2bf(hn);
      H0H[wp][cb * 512 + hb4 + chl] = hh;
      H0L[wp][cb * 512 + hb4 + chl] = f2bf(hn - bf2f(hh));
    }
    gridbar(bar, &phase);
    // ---------- layer 1: gates = h0[wp] @ w_ih1^T + h1[rp] @ w_hh1^T --------
    {
      f4v x_hh = {0.f, 0.f, 0.f, 0.f}, x_hl = x_hh, x_lh = x_hh;
      f4v h_hh = x_hh, h_hl = x_hh, h_lh = x_hh;
      const short* axh = H0H[wp] + foff;
      const short* axl = H0L[wp] + foff;
      const short* ahh = H1H[rp] + foff;
      const short* ahl = H1L[rp] + foff;
      const short* bxh = &wlds[2 * WROWS + woff];
      const short* bxl = &wlds[3 * WROWS + woff];
      const short* bhh = &wlds[4 * WROWS + woff];
      const short* bhl = &wlds[5 * WROWS + woff];
#pragma unroll
      for (int ks = 0; ks < 8; ++ks) {
        s8v Axh = *(const s8v*)(axh + ks * 32);
        s8v Axl = *(const s8v*)(axl + ks * 32);
        s8v Bxh = *(const s8v*)(bxh + ks * 32);
        s8v Bxl = *(const s8v*)(bxl + ks * 32);
        x_hh = __builtin_amdgcn_mfma_f32_16x16x32_bf16(Axh, Bxh, x_hh, 0, 0, 0);
        x_hl = __builtin_amdgcn_mfma_f32_16x16x32_bf16(Axh, Bxl, x_hl, 0, 0, 0);
        x_lh = __builtin_amdgcn_mfma_f32_16x16x32_bf16(Axl, Bxh, x_lh, 0, 0, 0);
        s8v Ahh = *(const s8v*)(ahh + ks * 32);
        s8v Ahl = *(const s8v*)(ahl + ks * 32);
        s8v Bhh = *(const s8v*)(bhh + ks * 32);
        s8v Bhl = *(const s8v*)(bhl + ks * 32);
        h_hh = __builtin_amdgcn_mfma_f32_16x16x32_bf16(Ahh, Bhh, h_hh, 0, 0, 0);
        h_hl = __builtin_amdgcn_mfma_f32_16x16x32_bf16(Ahh, Bhl, h_hl, 0, 0, 0);
        h_lh = __builtin_amdgcn_mfma_f32_16x16x32_bf16(Ahl, Bhh, h_lh, 0, 0, 0);
      }
      f4v acc = x_hh + x_hl + x_lh + h_hh + h_hl + h_lh;
#pragma unroll
      for (int r = 0; r < 4; ++r) gbuf[kh][mt * 16 + fq * 4 + r][fr] = acc[r];
    }
    __syncthreads();
    if (tid < 128) {
      float g4[4];
#pragma unroll
      for (int g = 0; g < 4; ++g) {
        int c = g * 4 + chl;
        g4[g] = gbuf[0][cb][c] + gbuf[1][cb][c] + bias1_l[c];
      }
      float cn = sigm(g4[1]) * c1r + sigm(g4[0]) * tanhf(g4[2]);
      float hn = sigm(g4[3]) * tanhf(cn);
      c1r = cn;
      short hh = f2bf(hn);
      H1H[wp][cb * 512 + hb4 + chl] = hh;
      H1L[wp][cb * 512 + hb4 + chl] = f2bf(hn - bf2f(hh));
      h1seq[((long)cb * 64 + t) * 512 + hb4 + chl] = hn;
    }
    gridbar(bar, &phase);
  }
}

extern "C" void kernel_launch(void* const* d_in, const int* in_sizes, int n_in,
                              void* d_out, int out_size, void* d_ws, size_t ws_size,
                              hipStream_t stream) {
  const int*   tokens  = (const int*)  d_in[0];
  const float* enc_out = (const float*)d_in[1];
  const float* enc_h   = (const float*)d_in[2];
  const float* enc_c   = (const float*)d_in[3];
  const float* emb     = (const float*)d_in[4];
  const float* attn1_w = (const float*)d_in[5];
  const float* attn2_w = (const float*)d_in[7];
  const float* w_ih0   = (const float*)d_in[9];
  const float* w_hh0   = (const float*)d_in[10];
  const float* b_ih0   = (const float*)d_in[11];
  const float* b_hh0   = (const float*)d_in[12];
  const float* w_ih1   = (const float*)d_in[13];
  const float* w_hh1   = (const float*)d_in[14];
  const float* b_ih1   = (const float*)d_in[15];
  const float* b_hh1   = (const float*)d_in[16];
  const float* out_w   = (const float*)d_in[17];
  const float* out_b   = (const float*)d_in[18];
  float* out = (float*)d_out;

  float* f = (float*)d_ws;
  float*    w_enc  = f;                       // 1024
  float*    ctx    = f + 1024;                // 32*1024
  float*    ctxpre = f + 33792;               // 32*2048
  float*    embpre = f + 99328;               // 2048*2048
  float*    h1seq  = f + 4293632;             // 2048*512
  short*    hbuf   = (short*)(f + 5342208);   // 131072 shorts (8 x [32][512])
  unsigned* bar    = (unsigned*)(f + 5407744);

  k_init2<<<64, 256, 0, stream>>>(enc_h, hbuf, bar);
  k_weff<<<32, 256, 0, stream>>>(attn1_w, attn2_w, w_enc);
  k_attn<<<32, 256, 0, stream>>>(enc_out, w_enc, ctx);
  k_ctxpre<<<256, 256, 0, stream>>>(w_ih0, b_ih0, b_hh0, ctx, ctxpre);
  // embpre[m][j] = emb[tokens[m]] . w_ih0[j, 0:512]   (cached stores: re-read soon)
  gemm_bf16_nt<false><<<dim3(16, 16), 256, 0, stream>>>(emb, w_ih0, tokens, nullptr,
                                                        embpre, 512, 512, 1536, 2048);
  lstm_persist<<<NBLK, 256, 0, stream>>>(w_hh0, w_ih1, w_hh1, b_ih1, b_hh1, enc_c,
                                         embpre, ctxpre, hbuf, h1seq, bar);
  // out[m][v] = h1seq[m] . out_w[v] + out_b[v]   (nontemporal C stores)
  gemm_bf16_nt<true><<<dim3(250, 16), 256, 0, stream>>>(h1seq, out_w, nullptr, out_b,
                                                        out, 512, 512, 512, 32000);
}

// Round 3
// 1253.890 us; speedup vs baseline: 4.2581x; 1.7764x over previous
//
#include <hip/hip_runtime.h>
#include <hip/hip_bf16.h>

typedef __attribute__((ext_vector_type(4))) float f4v;
typedef __attribute__((ext_vector_type(4))) short s4v;
typedef __attribute__((ext_vector_type(8))) short s8v;

#define DEVINL __device__ __forceinline__
#define NBLK 128
#define PADK 536          // 512 + 24 shorts padding
#define WROWS (16 * PADK) // shorts per weight slice

DEVINL short f2bf(float f) {
  unsigned u = __float_as_uint(f);
  u += 0x7FFFu + ((u >> 16) & 1u);
  return (short)(u >> 16);
}
DEVINL float bf2f(short s) {
  return __uint_as_float(((unsigned)(unsigned short)s) << 16);
}
DEVINL float sigm(float x) { return 1.f / (1.f + expf(-x)); }

// ---- contention-free gather/release grid barrier (128 blocks) --------------
// arr[b*32]: per-block arrival word (own cache line). rel: single release word.
DEVINL void gridbar2(unsigned* __restrict__ arr, unsigned* __restrict__ rel,
                     unsigned v) {
  const int tid = threadIdx.x;
  __syncthreads();  // all block stores drained (vmcnt0 before s_barrier)
  if (tid == 0) {
    __builtin_amdgcn_fence(__ATOMIC_RELEASE, "agent");
    __hip_atomic_store(&arr[(unsigned)blockIdx.x << 5], v, __ATOMIC_RELAXED,
                       __HIP_MEMORY_SCOPE_AGENT);
  }
  if (blockIdx.x == 0 && tid < NBLK) {
    while (__hip_atomic_load(&arr[tid << 5], __ATOMIC_RELAXED,
                             __HIP_MEMORY_SCOPE_AGENT) < v)
      __builtin_amdgcn_s_sleep(1);
  }
  __syncthreads();
  if (tid == 0) {
    if (blockIdx.x == 0) {
      __builtin_amdgcn_fence(__ATOMIC_ACQUIRE, "agent");
      __hip_atomic_store(rel, v, __ATOMIC_RELAXED, __HIP_MEMORY_SCOPE_AGENT);
    }
    while (__hip_atomic_load(rel, __ATOMIC_RELAXED,
                             __HIP_MEMORY_SCOPE_AGENT) < v)
      __builtin_amdgcn_s_sleep(1);
    __builtin_amdgcn_fence(__ATOMIC_ACQUIRE, "agent");
  }
  __syncthreads();
}

// ---- init: h0,h1 (bf16 hi/lo) into slot-1 buffers; zero barrier words ------
__global__ __launch_bounds__(256) void k_init2(const float* __restrict__ enc_h,
                                               short* __restrict__ hbuf,
                                               unsigned* __restrict__ arr) {
  int i = blockIdx.x * 256 + threadIdx.x;  // 0..16383
  float h0 = enc_h[i], h1 = enc_h[16384 + i];
  short h0h = f2bf(h0), h1h = f2bf(h1);
  hbuf[16384 + i] = h0h;                      // H0H slot1
  hbuf[3 * 16384 + i] = f2bf(h0 - bf2f(h0h)); // H0L slot1
  hbuf[5 * 16384 + i] = h1h;                  // H1H slot1
  hbuf[7 * 16384 + i] = f2bf(h1 - bf2f(h1h)); // H1L slot1
  if (i < NBLK * 32 + 32) arr[i] = 0u;
}

// ---- w_enc[j] = sum_k attn2_w[k] * attn1_w[k*2048 + j], j<1024 -------------
__global__ __launch_bounds__(256) void k_weff(const float* __restrict__ attn1_w,
                                              const float* __restrict__ attn2_w,
                                              float* __restrict__ w_enc) {
  __shared__ float part[8][32];
  int t = threadIdx.x;
  int jl = t & 31, kp = t >> 5;
  int j = blockIdx.x * 32 + jl;
  float acc = 0.f;
  for (int k = kp * 256; k < kp * 256 + 256; ++k)
    acc += attn2_w[k] * attn1_w[(long)k * 2048 + j];
  part[kp][jl] = acc;
  __syncthreads();
  if (t < 32) {
    float s = 0.f;
    for (int p = 0; p < 8; ++p) s += part[p][t];
    w_enc[blockIdx.x * 32 + t] = s;
  }
}

// ---- per-b: logits -> softmax -> ctx[b, 0:1024] ----------------------------
__global__ __launch_bounds__(256) void k_attn(const float* __restrict__ enc,
                                              const float* __restrict__ w_enc,
                                              float* __restrict__ ctx) {
  __shared__ float red[256];
  __shared__ float wls[128];
  int b = blockIdx.x, t = threadIdx.x;
  int s = t >> 1, half = t & 1;
  const float* e = enc + ((long)b * 128 + s) * 1024 + half * 512;
  const float* wv = w_enc + half * 512;
  float acc = 0.f;
  for (int k = 0; k < 512; k += 4) {
    f4v ev = *(const f4v*)(e + k);
    f4v w4 = *(const f4v*)(wv + k);
    acc += ev[0] * w4[0] + ev[1] * w4[1] + ev[2] * w4[2] + ev[3] * w4[3];
  }
  red[t] = acc;
  __syncthreads();
  if (half == 0) wls[s] = red[t] + red[t + 1];
  __syncthreads();
  red[t] = (t < 128) ? wls[t] : -3.4e38f;
  __syncthreads();
  for (int off = 128; off >= 1; off >>= 1) {
    if (t < off) red[t] = fmaxf(red[t], red[t + off]);
    __syncthreads();
  }
  float mx = red[0];
  __syncthreads();
  if (t < 128) { float ex = expf(wls[t] - mx); wls[t] = ex; red[t] = ex; }
  else red[t] = 0.f;
  __syncthreads();
  for (int off = 128; off >= 1; off >>= 1) {
    if (t < off) red[t] += red[t + off];
    __syncthreads();
  }
  float inv = 1.f / red[0];
  __syncthreads();
  if (t < 128) wls[t] *= inv;
  __syncthreads();
  float a0 = 0.f, a1 = 0.f, a2 = 0.f, a3 = 0.f;
  for (int ss = 0; ss < 128; ++ss) {
    float w = wls[ss];
    const float* er = enc + ((long)b * 128 + ss) * 1024;
    a0 += w * er[t];
    a1 += w * er[t + 256];
    a2 += w * er[t + 512];
    a3 += w * er[t + 768];
  }
  ctx[b * 1024 + t] = a0;
  ctx[b * 1024 + t + 256] = a1;
  ctx[b * 1024 + t + 512] = a2;
  ctx[b * 1024 + t + 768] = a3;
}

// ---- ctxpre[b][j] = ctx[b] . w_ih0[j, 512:1536] + b_ih0[j] + b_hh0[j] ------
__global__ __launch_bounds__(256) void k_ctxpre(const float* __restrict__ w_ih0,
                                                const float* __restrict__ b_ih0,
                                                const float* __restrict__ b_hh0,
                                                const float* __restrict__ ctx,
                                                float* __restrict__ ctxpre) {
  int t = threadIdx.x;
  int j = blockIdx.x * 8 + (t >> 5);
  int b = t & 31;
  float acc = b_ih0[j] + b_hh0[j];
  const float* w = w_ih0 + (long)j * 1536 + 512;
  const float* c = ctx + b * 1024;
  for (int k = 0; k < 1024; k += 4) {
    f4v wv = *(const f4v*)(w + k);
    f4v cv = *(const f4v*)(c + k);
    acc += wv[0] * cv[0] + wv[1] * cv[1] + wv[2] * cv[2] + wv[3] * cv[3];
  }
  ctxpre[b * 2048 + j] = acc;
}

// ---- bf16 MFMA GEMM: C[m][n] = A[m,:].B[n,:] (+bias) -----------------------
// MODE 0: normal store. MODE 1: nontemporal store + swapped grid (m on x).
// MODE 2: scatter to embp2[bz][t][b][c] packed layout (C = embp2 base).
template <int MODE>
__global__ __launch_bounds__(256) void gemm_bf16(
    const float* __restrict__ A, const float* __restrict__ B,
    const int* __restrict__ a_rows, const float* __restrict__ bias,
    float* __restrict__ C, int K, int lda, int ldb, int ldc) {
  __shared__ short As[128 * 72];
  __shared__ short Bs[128 * 72];
  int n0, m0;
  if (MODE == 1) { m0 = blockIdx.x * 128; n0 = blockIdx.y * 128; }
  else           { n0 = blockIdx.x * 128; m0 = blockIdx.y * 128; }
  int t = threadIdx.x;
  int lane = t & 63, w = t >> 6;
  int wm = w & 1, wn = w >> 1;
  f4v acc[4][4];
#pragma unroll
  for (int mi = 0; mi < 4; ++mi)
#pragma unroll
    for (int ni = 0; ni < 4; ++ni) acc[mi][ni] = (f4v){0.f, 0.f, 0.f, 0.f};

  int sr = t >> 1;
  int sh = (t & 1) * 32;
  long arow = a_rows ? (long)a_rows[m0 + sr] : (long)(m0 + sr);
  const float* ap = A + arow * lda + sh;
  const float* bp = B + (long)(n0 + sr) * ldb + sh;
  short* as = &As[sr * 72 + sh];
  short* bs = &Bs[sr * 72 + sh];

  for (int k0 = 0; k0 < K; k0 += 64) {
#pragma unroll
    for (int i = 0; i < 8; ++i) {
      f4v va = *(const f4v*)(ap + k0 + i * 4);
      f4v vb = *(const f4v*)(bp + k0 + i * 4);
      s4v sa, sb;
      sa[0] = f2bf(va[0]); sa[1] = f2bf(va[1]); sa[2] = f2bf(va[2]); sa[3] = f2bf(va[3]);
      sb[0] = f2bf(vb[0]); sb[1] = f2bf(vb[1]); sb[2] = f2bf(vb[2]); sb[3] = f2bf(vb[3]);
      *(s4v*)(as + i * 4) = sa;
      *(s4v*)(bs + i * 4) = sb;
    }
    __syncthreads();
#pragma unroll
    for (int ks = 0; ks < 2; ++ks) {
      s8v af[4], bf[4];
#pragma unroll
      for (int mi = 0; mi < 4; ++mi)
        af[mi] = *(const s8v*)&As[(wm * 64 + mi * 16 + (lane & 15)) * 72 + ks * 32 + (lane >> 4) * 8];
#pragma unroll
      for (int ni = 0; ni < 4; ++ni)
        bf[ni] = *(const s8v*)&Bs[(wn * 64 + ni * 16 + (lane & 15)) * 72 + ks * 32 + (lane >> 4) * 8];
#pragma unroll
      for (int mi = 0; mi < 4; ++mi)
#pragma unroll
        for (int ni = 0; ni < 4; ++ni)
          acc[mi][ni] = __builtin_amdgcn_mfma_f32_16x16x32_bf16(af[mi], bf[ni], acc[mi][ni], 0, 0, 0);
    }
    __syncthreads();
  }
  int fq = lane >> 4, fr = lane & 15;
#pragma unroll
  for (int mi = 0; mi < 4; ++mi)
#pragma unroll
    for (int ni = 0; ni < 4; ++ni) {
      int col = n0 + wn * 64 + ni * 16 + fr;
      long rowb = m0 + wm * 64 + mi * 16 + fq * 4;
      if (MODE == 2) {
        int bz = (col & 511) >> 2;
        int c = ((col >> 9) << 2) + (col & 3);
#pragma unroll
        for (int r = 0; r < 4; ++r) {
          long m = rowb + r;  // = b*64 + t
          C[(long)bz * 32768 + (m & 63) * 512 + (m >> 6) * 16 + c] = acc[mi][ni][r];
        }
      } else {
        float bv = bias ? bias[col] : 0.f;
#pragma unroll
        for (int r = 0; r < 4; ++r) {
          float val = acc[mi][ni][r] + bv;
          float* cp = &C[(rowb + r) * (long)ldc + col];
          if (MODE == 1) __builtin_nontemporal_store(val, cp);
          else *cp = val;
        }
      }
    }
}

// ---- persistent fused 2-layer LSTM: 65 phases, 1 grid barrier each ---------
// Phase p: layer1(t=p-1) [needs h0(p-1), h1(p-2)] and layer0(t=p) [needs h0(p-1)]
// computed in one fused MFMA pass (h0(p-1) A-fragments shared). h(t) lives in
// global bf16 hi/lo slot t&1; initial states in slot 1. c-states in registers.
__global__ __launch_bounds__(256, 1) void lstm_persist(
    const float* __restrict__ w_hh0, const float* __restrict__ w_ih1,
    const float* __restrict__ w_hh1,
    const float* __restrict__ b_ih1, const float* __restrict__ b_hh1,
    const float* __restrict__ enc_c,
    const float* __restrict__ embp2, const float* __restrict__ ctxpre,
    short* __restrict__ hbuf, float* __restrict__ h1seq,
    unsigned* __restrict__ arr, unsigned* __restrict__ rel) {
  __shared__ alignas(16) short wlds[6 * WROWS];  // w0 h/l, w1ih h/l, w1hh h/l
  __shared__ float ctxp_l[32][16];
  __shared__ float bias1_l[16];
  __shared__ float gbuf[2][2][32][17];           // [layer][kh][row][col]

  const int tid = threadIdx.x;
  const int hb4 = blockIdx.x * 4;
  const int lane = tid & 63, wid = tid >> 6;
  const int mt = wid & 1, kh = wid >> 1;
  const int fr = lane & 15, fq = lane >> 4;

  // stage weight slices (rows c = gate*4 + hlocal)
  for (int base = tid * 4; base < 48 * 512; base += 1024) {
    int row = base >> 9, k = base & 511;
    int m = row >> 4, c = row & 15;
    int j = ((c >> 2) << 9) + hb4 + (c & 3);
    const float* wsrc = (m == 0) ? w_hh0 : ((m == 1) ? w_ih1 : w_hh1);
    f4v v = *(const f4v*)(wsrc + (long)j * 512 + k);
    short* hi = &wlds[(m * 2) * WROWS + c * PADK + k];
    short* lo = &wlds[(m * 2 + 1) * WROWS + c * PADK + k];
#pragma unroll
    for (int e = 0; e < 4; ++e) {
      short hh = f2bf(v[e]);
      hi[e] = hh;
      lo[e] = f2bf(v[e] - bf2f(hh));
    }
  }
  for (int i = tid; i < 512; i += 256) {
    int b = i >> 4, c = i & 15;
    ctxp_l[b][c] = ctxpre[b * 2048 + ((c >> 2) << 9) + hb4 + (c & 3)];
  }
  if (tid < 16) {
    int j = ((tid >> 2) << 9) + hb4 + (tid & 3);
    bias1_l[tid] = b_ih1[j] + b_hh1[j];
  }
  const int cb = tid & 31, chl = (tid >> 5) & 3;
  float c0r = 0.f, c1r = 0.f;
  if (tid < 128) c0r = enc_c[cb * 512 + hb4 + chl];
  else           c1r = enc_c[16384 + cb * 512 + hb4 + chl];
  __syncthreads();

  short* H0H[2] = {hbuf, hbuf + 16384};
  short* H0L[2] = {hbuf + 32768, hbuf + 49152};
  short* H1H[2] = {hbuf + 65536, hbuf + 81920};
  short* H1L[2] = {hbuf + 98304, hbuf + 114688};
  const int foff = (mt * 16 + fr) * 512 + kh * 256 + fq * 8;
  const int woff = fr * PADK + kh * 256 + fq * 8;

  for (int p = 0; p <= 64; ++p) {
    const int a = p & 1, r0 = 1 - a;
    const bool do_l0 = (p < 64), do_l1 = (p > 0);
    // prefetch embp2 for layer0 step t0=p (contiguous 2KB per block)
    float e4[4] = {0.f, 0.f, 0.f, 0.f};
    if (do_l0 && tid < 128) {
      const float* ep = embp2 + (long)blockIdx.x * 32768 + p * 512 + cb * 16 + chl;
#pragma unroll
      for (int g = 0; g < 4; ++g) e4[g] = ep[g * 4];
    }
    {
      f4v l0hh = {0.f, 0.f, 0.f, 0.f}, l0hl = l0hh, l0lh = l0hh;
      f4v x1hh = l0hh, x1hl = l0hh, x1lh = l0hh;
      f4v h1hh = l0hh, h1hl = l0hh, h1lh = l0hh;
      const short* a0h = H0H[r0] + foff;
      const short* a0l = H0L[r0] + foff;
      const short* a1h = H1H[a] + foff;
      const short* a1l = H1L[a] + foff;
      const short* b0h = &wlds[0 * WROWS + woff];
      const short* b0l = &wlds[1 * WROWS + woff];
      const short* b2h = &wlds[2 * WROWS + woff];
      const short* b2l = &wlds[3 * WROWS + woff];
      const short* b4h = &wlds[4 * WROWS + woff];
      const short* b4l = &wlds[5 * WROWS + woff];
#pragma unroll
      for (int ks = 0; ks < 8; ++ks) {
        s8v A0h = *(const s8v*)(a0h + ks * 32);
        s8v A0l = *(const s8v*)(a0l + ks * 32);
        if (do_l0) {
          s8v B0h = *(const s8v*)(b0h + ks * 32);
          s8v B0l = *(const s8v*)(b0l + ks * 32);
          l0hh = __builtin_amdgcn_mfma_f32_16x16x32_bf16(A0h, B0h, l0hh, 0, 0, 0);
          l0hl = __builtin_amdgcn_mfma_f32_16x16x32_bf16(A0h, B0l, l0hl, 0, 0, 0);
          l0lh = __builtin_amdgcn_mfma_f32_16x16x32_bf16(A0l, B0h, l0lh, 0, 0, 0);
        }
        if (do_l1) {
          s8v B2h = *(const s8v*)(b2h + ks * 32);
          s8v B2l = *(const s8v*)(b2l + ks * 32);
          x1hh = __builtin_amdgcn_mfma_f32_16x16x32_bf16(A0h, B2h, x1hh, 0, 0, 0);
          x1hl = __builtin_amdgcn_mfma_f32_16x16x32_bf16(A0h, B2l, x1hl, 0, 0, 0);
          x1lh = __builtin_amdgcn_mfma_f32_16x16x32_bf16(A0l, B2h, x1lh, 0, 0, 0);
          s8v A1h = *(const s8v*)(a1h + ks * 32);
          s8v A1l = *(const s8v*)(a1l + ks * 32);
          s8v B4h = *(const s8v*)(b4h + ks * 32);
          s8v B4l = *(const s8v*)(b4l + ks * 32);
          h1hh = __builtin_amdgcn_mfma_f32_16x16x32_bf16(A1h, B4h, h1hh, 0, 0, 0);
          h1hl = __builtin_amdgcn_mfma_f32_16x16x32_bf16(A1h, B4l, h1hl, 0, 0, 0);
          h1lh = __builtin_amdgcn_mfma_f32_16x16x32_bf16(A1l, B4h, h1lh, 0, 0, 0);
        }
      }
      if (do_l0) {
        f4v s = l0hh + l0hl + l0lh;
#pragma unroll
        for (int r = 0; r < 4; ++r) gbuf[0][kh][mt * 16 + fq * 4 + r][fr] = s[r];
      }
      if (do_l1) {
        f4v s = x1hh + x1hl + x1lh + h1hh + h1hl + h1lh;
#pragma unroll
        for (int r = 0; r < 4; ++r) gbuf[1][kh][mt * 16 + fq * 4 + r][fr] = s[r];
      }
    }
    __syncthreads();
    if (tid < 128) {
      if (do_l0) {
        float g4[4];
#pragma unroll
        for (int g = 0; g < 4; ++g) {
          int c = g * 4 + chl;
          g4[g] = gbuf[0][0][cb][c] + gbuf[0][1][cb][c] + ctxp_l[cb][c] + e4[g];
        }
        float cn = sigm(g4[1]) * c0r + sigm(g4[0]) * tanhf(g4[2]);
        float hn = sigm(g4[3]) * tanhf(cn);
        c0r = cn;
        short hh = f2bf(hn);
        H0H[a][cb * 512 + hb4 + chl] = hh;
        H0L[a][cb * 512 + hb4 + chl] = f2bf(hn - bf2f(hh));
      }
    } else if (do_l1) {
      float g4[4];
#pragma unroll
      for (int g = 0; g < 4; ++g) {
        int c = g * 4 + chl;
        g4[g] = gbuf[1][0][cb][c] + gbuf[1][1][cb][c] + bias1_l[c];
      }
      float cn = sigm(g4[1]) * c1r + sigm(g4[0]) * tanhf(g4[2]);
      float hn = sigm(g4[3]) * tanhf(cn);
      c1r = cn;
      short hh = f2bf(hn);
      H1H[r0][cb * 512 + hb4 + chl] = hh;
      H1L[r0][cb * 512 + hb4 + chl] = f2bf(hn - bf2f(hh));
      h1seq[((long)cb * 64 + (p - 1)) * 512 + hb4 + chl] = hn;
    }
    gridbar2(arr, rel, (unsigned)(p + 1));
  }
}

extern "C" void kernel_launch(void* const* d_in, const int* in_sizes, int n_in,
                              void* d_out, int out_size, void* d_ws, size_t ws_size,
                              hipStream_t stream) {
  const int*   tokens  = (const int*)  d_in[0];
  const float* enc_out = (const float*)d_in[1];
  const float* enc_h   = (const float*)d_in[2];
  const float* enc_c   = (const float*)d_in[3];
  const float* emb     = (const float*)d_in[4];
  const float* attn1_w = (const float*)d_in[5];
  const float* attn2_w = (const float*)d_in[7];
  const float* w_ih0   = (const float*)d_in[9];
  const float* w_hh0   = (const float*)d_in[10];
  const float* b_ih0   = (const float*)d_in[11];
  const float* b_hh0   = (const float*)d_in[12];
  const float* w_ih1   = (const float*)d_in[13];
  const float* w_hh1   = (const float*)d_in[14];
  const float* b_ih1   = (const float*)d_in[15];
  const float* b_hh1   = (const float*)d_in[16];
  const float* out_w   = (const float*)d_in[17];
  const float* out_b   = (const float*)d_in[18];
  float* out = (float*)d_out;

  float* f = (float*)d_ws;
  float*    w_enc  = f;                       // 1024
  float*    ctx    = f + 1024;                // 32*1024
  float*    ctxpre = f + 33792;               // 32*2048
  float*    embp2  = f + 99328;               // 128*64*32*16 = 4M floats
  float*    h1seq  = f + 4293632;             // 2048*512
  short*    hbuf   = (short*)(f + 5342208);   // 8 x 16384 shorts
  unsigned* arr    = (unsigned*)(f + 5407744);// 128*32 + rel
  unsigned* rel    = arr + NBLK * 32;

  k_init2<<<64, 256, 0, stream>>>(enc_h, hbuf, arr);
  k_weff<<<32, 256, 0, stream>>>(attn1_w, attn2_w, w_enc);
  k_attn<<<32, 256, 0, stream>>>(enc_out, w_enc, ctx);
  k_ctxpre<<<256, 256, 0, stream>>>(w_ih0, b_ih0, b_hh0, ctx, ctxpre);
  // embp2[bz][t][b][c] <- emb[tokens[m]] . w_ih0[j,0:512]  (packed scatter)
  gemm_bf16<2><<<dim3(16, 16), 256, 0, stream>>>(emb, w_ih0, tokens, nullptr,
                                                 embp2, 512, 512, 1536, 0);
  lstm_persist<<<NBLK, 256, 0, stream>>>(w_hh0, w_ih1, w_hh1, b_ih1, b_hh1, enc_c,
                                         embp2, ctxpre, hbuf, h1seq, arr, rel);
  // out[m][v] = h1seq[m] . out_w[v] + out_b[v]  (m on blockIdx.x for B-reuse)
  gemm_bf16<1><<<dim3(16, 250), 256, 0, stream>>>(h1seq, out_w, nullptr, out_b,
                                                  out, 512, 512, 512, 32000);
}

// Round 4
// 1055.714 us; speedup vs baseline: 5.0575x; 1.1877x over previous
//
#include <hip/hip_runtime.h>
#include <hip/hip_bf16.h>

typedef __attribute__((ext_vector_type(4))) float f4v;
typedef __attribute__((ext_vector_type(4))) short s4v;
typedef __attribute__((ext_vector_type(8))) short s8v;

#define DEVINL __device__ __forceinline__
#define NBLK 128
#define PADK 536          // 512 + 24 shorts padding
#define WROWS (16 * PADK) // shorts per weight slice

DEVINL short f2bf(float f) {
  unsigned u = __float_as_uint(f);
  u += 0x7FFFu + ((u >> 16) & 1u);
  return (short)(u >> 16);
}
DEVINL float bf2f(short s) {
  return __uint_as_float(((unsigned)(unsigned short)s) << 16);
}
DEVINL float sigm(float x) { return 1.f / (1.f + expf(-x)); }

// coherent (write-through past L2) 16-bit store
DEVINL void cstore16(short* p, short v) {
  asm volatile("global_store_short %0, %1, off sc0 sc1"
               :: "v"(p), "v"((unsigned)(unsigned short)v) : "memory");
}

// ---- init: h0,h1 (bf16 hi/lo) into slot-1 buffers; zero flag words ---------
__global__ __launch_bounds__(256) void k_init2(const float* __restrict__ enc_h,
                                               short* __restrict__ hbuf,
                                               unsigned* __restrict__ arr) {
  int i = blockIdx.x * 256 + threadIdx.x;  // 0..16383
  float h0 = enc_h[i], h1 = enc_h[16384 + i];
  short h0h = f2bf(h0), h1h = f2bf(h1);
  hbuf[16384 + i] = h0h;                      // H0H slot1
  hbuf[3 * 16384 + i] = f2bf(h0 - bf2f(h0h)); // H0L slot1
  hbuf[5 * 16384 + i] = h1h;                  // H1H slot1
  hbuf[7 * 16384 + i] = f2bf(h1 - bf2f(h1h)); // H1L slot1
  if (i < NBLK * 32 + 32) arr[i] = 0u;
}

// ---- w_enc[j] = sum_k attn2_w[k] * attn1_w[k*2048 + j], j<1024 -------------
__global__ __launch_bounds__(256) void k_weff(const float* __restrict__ attn1_w,
                                              const float* __restrict__ attn2_w,
                                              float* __restrict__ w_enc) {
  __shared__ float part[8][32];
  int t = threadIdx.x;
  int jl = t & 31, kp = t >> 5;
  int j = blockIdx.x * 32 + jl;
  float acc = 0.f;
  for (int k = kp * 256; k < kp * 256 + 256; ++k)
    acc += attn2_w[k] * attn1_w[(long)k * 2048 + j];
  part[kp][jl] = acc;
  __syncthreads();
  if (t < 32) {
    float s = 0.f;
    for (int p = 0; p < 8; ++p) s += part[p][t];
    w_enc[blockIdx.x * 32 + t] = s;
  }
}

// ---- per-b: logits -> softmax -> ctx[b, 0:1024] ----------------------------
__global__ __launch_bounds__(256) void k_attn(const float* __restrict__ enc,
                                              const float* __restrict__ w_enc,
                                              float* __restrict__ ctx) {
  __shared__ float red[256];
  __shared__ float wls[128];
  int b = blockIdx.x, t = threadIdx.x;
  int s = t >> 1, half = t & 1;
  const float* e = enc + ((long)b * 128 + s) * 1024 + half * 512;
  const float* wv = w_enc + half * 512;
  float acc = 0.f;
  for (int k = 0; k < 512; k += 4) {
    f4v ev = *(const f4v*)(e + k);
    f4v w4 = *(const f4v*)(wv + k);
    acc += ev[0] * w4[0] + ev[1] * w4[1] + ev[2] * w4[2] + ev[3] * w4[3];
  }
  red[t] = acc;
  __syncthreads();
  if (half == 0) wls[s] = red[t] + red[t + 1];
  __syncthreads();
  red[t] = (t < 128) ? wls[t] : -3.4e38f;
  __syncthreads();
  for (int off = 128; off >= 1; off >>= 1) {
    if (t < off) red[t] = fmaxf(red[t], red[t + off]);
    __syncthreads();
  }
  float mx = red[0];
  __syncthreads();
  if (t < 128) { float ex = expf(wls[t] - mx); wls[t] = ex; red[t] = ex; }
  else red[t] = 0.f;
  __syncthreads();
  for (int off = 128; off >= 1; off >>= 1) {
    if (t < off) red[t] += red[t + off];
    __syncthreads();
  }
  float inv = 1.f / red[0];
  __syncthreads();
  if (t < 128) wls[t] *= inv;
  __syncthreads();
  float a0 = 0.f, a1 = 0.f, a2 = 0.f, a3 = 0.f;
  for (int ss = 0; ss < 128; ++ss) {
    float w = wls[ss];
    const float* er = enc + ((long)b * 128 + ss) * 1024;
    a0 += w * er[t];
    a1 += w * er[t + 256];
    a2 += w * er[t + 512];
    a3 += w * er[t + 768];
  }
  ctx[b * 1024 + t] = a0;
  ctx[b * 1024 + t + 256] = a1;
  ctx[b * 1024 + t + 512] = a2;
  ctx[b * 1024 + t + 768] = a3;
}

// ---- ctxpre[b][j] = ctx[b] . w_ih0[j, 512:1536] + b_ih0[j] + b_hh0[j] ------
__global__ __launch_bounds__(256) void k_ctxpre(const float* __restrict__ w_ih0,
                                                const float* __restrict__ b_ih0,
                                                const float* __restrict__ b_hh0,
                                                const float* __restrict__ ctx,
                                                float* __restrict__ ctxpre) {
  int t = threadIdx.x;
  int j = blockIdx.x * 8 + (t >> 5);
  int b = t & 31;
  float acc = b_ih0[j] + b_hh0[j];
  const float* w = w_ih0 + (long)j * 1536 + 512;
  const float* c = ctx + b * 1024;
  for (int k = 0; k < 1024; k += 4) {
    f4v wv = *(const f4v*)(w + k);
    f4v cv = *(const f4v*)(c + k);
    acc += wv[0] * cv[0] + wv[1] * cv[1] + wv[2] * cv[2] + wv[3] * cv[3];
  }
  ctxpre[b * 2048 + j] = acc;
}

// ---- fp32 out_w -> bf16 --------------------------------------------------
__global__ __launch_bounds__(256) void k_cvt(const float* __restrict__ src,
                                             short* __restrict__ dst) {
  long i = ((long)blockIdx.x * 256 + threadIdx.x) * 8;
  f4v a = *(const f4v*)(src + i);
  f4v b = *(const f4v*)(src + i + 4);
  s8v o;
  o[0] = f2bf(a[0]); o[1] = f2bf(a[1]); o[2] = f2bf(a[2]); o[3] = f2bf(a[3]);
  o[4] = f2bf(b[0]); o[5] = f2bf(b[1]); o[6] = f2bf(b[2]); o[7] = f2bf(b[3]);
  *(s8v*)(dst + i) = o;
}

// ---- fp32-input bf16 MFMA GEMM (MODE 2: scatter to embp2 packed layout) ----
template <int MODE>
__global__ __launch_bounds__(256) void gemm_bf16(
    const float* __restrict__ A, const float* __restrict__ B,
    const int* __restrict__ a_rows, const float* __restrict__ bias,
    float* __restrict__ C, int K, int lda, int ldb, int ldc) {
  __shared__ short As[128 * 72];
  __shared__ short Bs[128 * 72];
  int n0 = blockIdx.x * 128, m0 = blockIdx.y * 128;
  int t = threadIdx.x;
  int lane = t & 63, w = t >> 6;
  int wm = w & 1, wn = w >> 1;
  f4v acc[4][4];
#pragma unroll
  for (int mi = 0; mi < 4; ++mi)
#pragma unroll
    for (int ni = 0; ni < 4; ++ni) acc[mi][ni] = (f4v){0.f, 0.f, 0.f, 0.f};

  int sr = t >> 1;
  int sh = (t & 1) * 32;
  long arow = a_rows ? (long)a_rows[m0 + sr] : (long)(m0 + sr);
  const float* ap = A + arow * lda + sh;
  const float* bp = B + (long)(n0 + sr) * ldb + sh;
  short* as = &As[sr * 72 + sh];
  short* bs = &Bs[sr * 72 + sh];

  for (int k0 = 0; k0 < K; k0 += 64) {
#pragma unroll
    for (int i = 0; i < 8; ++i) {
      f4v va = *(const f4v*)(ap + k0 + i * 4);
      f4v vb = *(const f4v*)(bp + k0 + i * 4);
      s4v sa, sb;
      sa[0] = f2bf(va[0]); sa[1] = f2bf(va[1]); sa[2] = f2bf(va[2]); sa[3] = f2bf(va[3]);
      sb[0] = f2bf(vb[0]); sb[1] = f2bf(vb[1]); sb[2] = f2bf(vb[2]); sb[3] = f2bf(vb[3]);
      *(s4v*)(as + i * 4) = sa;
      *(s4v*)(bs + i * 4) = sb;
    }
    __syncthreads();
#pragma unroll
    for (int ks = 0; ks < 2; ++ks) {
      s8v af[4], bf[4];
#pragma unroll
      for (int mi = 0; mi < 4; ++mi)
        af[mi] = *(const s8v*)&As[(wm * 64 + mi * 16 + (lane & 15)) * 72 + ks * 32 + (lane >> 4) * 8];
#pragma unroll
      for (int ni = 0; ni < 4; ++ni)
        bf[ni] = *(const s8v*)&Bs[(wn * 64 + ni * 16 + (lane & 15)) * 72 + ks * 32 + (lane >> 4) * 8];
#pragma unroll
      for (int mi = 0; mi < 4; ++mi)
#pragma unroll
        for (int ni = 0; ni < 4; ++ni)
          acc[mi][ni] = __builtin_amdgcn_mfma_f32_16x16x32_bf16(af[mi], bf[ni], acc[mi][ni], 0, 0, 0);
    }
    __syncthreads();
  }
  int fq = lane >> 4, fr = lane & 15;
#pragma unroll
  for (int mi = 0; mi < 4; ++mi)
#pragma unroll
    for (int ni = 0; ni < 4; ++ni) {
      int col = n0 + wn * 64 + ni * 16 + fr;
      long rowb = m0 + wm * 64 + mi * 16 + fq * 4;
      if (MODE == 2) {
        int bz = (col & 511) >> 2;
        int c = ((col >> 9) << 2) + (col & 3);
#pragma unroll
        for (int r = 0; r < 4; ++r) {
          long m = rowb + r;  // = b*64 + t
          C[(long)bz * 32768 + (m & 63) * 512 + (m >> 6) * 16 + c] = acc[mi][ni][r];
        }
      } else {
        float bv = bias ? bias[col] : 0.f;
#pragma unroll
        for (int r = 0; r < 4; ++r) C[(rowb + r) * (long)ldc + col] = acc[mi][ni][r] + bv;
      }
    }
}

// ---- output GEMM: A bf16 [2048][512], B bf16 (or fp32 if BCVT) [32000][512] -
// grid: x = m-tiles (16), y = n-tiles (250) so B n-slices stay L2-hot.
template <bool BCVT>
__global__ __launch_bounds__(256) void gemm_out(
    const short* __restrict__ A, const short* __restrict__ Bbf,
    const float* __restrict__ Bf, const float* __restrict__ bias,
    float* __restrict__ C) {
  __shared__ short As[128 * 72];
  __shared__ short Bs[128 * 72];
  int m0 = blockIdx.x * 128, n0 = blockIdx.y * 128;
  int t = threadIdx.x;
  int lane = t & 63, w = t >> 6;
  int wm = w & 1, wn = w >> 1;
  f4v acc[4][4];
#pragma unroll
  for (int mi = 0; mi < 4; ++mi)
#pragma unroll
    for (int ni = 0; ni < 4; ++ni) acc[mi][ni] = (f4v){0.f, 0.f, 0.f, 0.f};

  int sr = t >> 1;
  int sh = (t & 1) * 32;
  const short* ap = A + (long)(m0 + sr) * 512 + sh;
  const short* bpb = Bbf + (long)(n0 + sr) * 512 + sh;
  const float* bpf = Bf + (long)(n0 + sr) * 512 + sh;
  short* as = &As[sr * 72 + sh];
  short* bs = &Bs[sr * 72 + sh];

  for (int k0 = 0; k0 < 512; k0 += 64) {
#pragma unroll
    for (int i = 0; i < 4; ++i)
      *(s8v*)(as + i * 8) = *(const s8v*)(ap + k0 + i * 8);
    if (BCVT) {
#pragma unroll
      for (int i = 0; i < 8; ++i) {
        f4v vb = *(const f4v*)(bpf + k0 + i * 4);
        s4v sb;
        sb[0] = f2bf(vb[0]); sb[1] = f2bf(vb[1]); sb[2] = f2bf(vb[2]); sb[3] = f2bf(vb[3]);
        *(s4v*)(bs + i * 4) = sb;
      }
    } else {
#pragma unroll
      for (int i = 0; i < 4; ++i)
        *(s8v*)(bs + i * 8) = *(const s8v*)(bpb + k0 + i * 8);
    }
    __syncthreads();
#pragma unroll
    for (int ks = 0; ks < 2; ++ks) {
      s8v af[4], bf[4];
#pragma unroll
      for (int mi = 0; mi < 4; ++mi)
        af[mi] = *(const s8v*)&As[(wm * 64 + mi * 16 + (lane & 15)) * 72 + ks * 32 + (lane >> 4) * 8];
#pragma unroll
      for (int ni = 0; ni < 4; ++ni)
        bf[ni] = *(const s8v*)&Bs[(wn * 64 + ni * 16 + (lane & 15)) * 72 + ks * 32 + (lane >> 4) * 8];
#pragma unroll
      for (int mi = 0; mi < 4; ++mi)
#pragma unroll
        for (int ni = 0; ni < 4; ++ni)
          acc[mi][ni] = __builtin_amdgcn_mfma_f32_16x16x32_bf16(af[mi], bf[ni], acc[mi][ni], 0, 0, 0);
    }
    __syncthreads();
  }
  int fq = lane >> 4, fr = lane & 15;
#pragma unroll
  for (int mi = 0; mi < 4; ++mi)
#pragma unroll
    for (int ni = 0; ni < 4; ++ni) {
      int col = n0 + wn * 64 + ni * 16 + fr;
      float bv = bias[col];
      long rowb = m0 + wm * 64 + mi * 16 + fq * 4;
#pragma unroll
      for (int r = 0; r < 4; ++r)
        __builtin_nontemporal_store(acc[mi][ni][r] + bv, &C[(rowb + r) * 32000L + col]);
    }
}

// ---- persistent fused 2-layer LSTM: 65 phases, fence-free flag barrier -----
__global__ __launch_bounds__(256, 1) void lstm_persist(
    const float* __restrict__ w_hh0, const float* __restrict__ w_ih1,
    const float* __restrict__ w_hh1,
    const float* __restrict__ b_ih1, const float* __restrict__ b_hh1,
    const float* __restrict__ enc_c,
    const float* __restrict__ embp2, const float* __restrict__ ctxpre,
    short* __restrict__ hbuf, short* __restrict__ h1seqbf,
    unsigned* __restrict__ arr) {
  __shared__ alignas(16) short wlds[6 * WROWS];  // w0 h/l, w1ih h/l, w1hh h/l
  __shared__ float ctxp_l[32][16];
  __shared__ float bias1_l[16];
  __shared__ float gbuf[2][2][32][17];           // [layer][kh][row][col]

  const int tid = threadIdx.x;
  const int hb4 = blockIdx.x * 4;
  const int lane = tid & 63, wid = tid >> 6;
  const int mt = wid & 1, kh = wid >> 1;
  const int fr = lane & 15, fq = lane >> 4;

  // stage weight slices (rows c = gate*4 + hlocal)
  for (int base = tid * 4; base < 48 * 512; base += 1024) {
    int row = base >> 9, k = base & 511;
    int m = row >> 4, c = row & 15;
    int j = ((c >> 2) << 9) + hb4 + (c & 3);
    const float* wsrc = (m == 0) ? w_hh0 : ((m == 1) ? w_ih1 : w_hh1);
    f4v v = *(const f4v*)(wsrc + (long)j * 512 + k);
    short* hi = &wlds[(m * 2) * WROWS + c * PADK + k];
    short* lo = &wlds[(m * 2 + 1) * WROWS + c * PADK + k];
#pragma unroll
    for (int e = 0; e < 4; ++e) {
      short hh = f2bf(v[e]);
      hi[e] = hh;
      lo[e] = f2bf(v[e] - bf2f(hh));
    }
  }
  for (int i = tid; i < 512; i += 256) {
    int b = i >> 4, c = i & 15;
    ctxp_l[b][c] = ctxpre[b * 2048 + ((c >> 2) << 9) + hb4 + (c & 3)];
  }
  if (tid < 16) {
    int j = ((tid >> 2) << 9) + hb4 + (tid & 3);
    bias1_l[tid] = b_ih1[j] + b_hh1[j];
  }
  const int cb = tid & 31, chl = (tid >> 5) & 3;
  float c0r = 0.f, c1r = 0.f;
  if (tid < 128) c0r = enc_c[cb * 512 + hb4 + chl];
  else           c1r = enc_c[16384 + cb * 512 + hb4 + chl];
  __syncthreads();

  short* H0H[2] = {hbuf, hbuf + 16384};
  short* H0L[2] = {hbuf + 32768, hbuf + 49152};
  short* H1H[2] = {hbuf + 65536, hbuf + 81920};
  short* H1L[2] = {hbuf + 98304, hbuf + 114688};
  const int foff = (mt * 16 + fr) * 512 + kh * 256 + fq * 8;
  const int woff = fr * PADK + kh * 256 + fq * 8;

  for (int p = 0; p <= 64; ++p) {
    const int a = p & 1, r0 = 1 - a;
    const bool do_l0 = (p < 64), do_l1 = (p > 0);
    if (p) {
      // all blocks gather all 128 flags (one hop), then invalidate clean lines
      if (tid < NBLK)
        while (__hip_atomic_load(&arr[tid << 5], __ATOMIC_RELAXED,
                                 __HIP_MEMORY_SCOPE_AGENT) < (unsigned)p)
          __builtin_amdgcn_s_sleep(1);
      __syncthreads();
      asm volatile("buffer_inv sc1" ::: "memory");
    }
    // prefetch embp2 for layer0 step t0=p (contiguous 2KB per block)
    float e4[4] = {0.f, 0.f, 0.f, 0.f};
    if (do_l0 && tid < 128) {
      const float* ep = embp2 + (long)blockIdx.x * 32768 + p * 512 + cb * 16 + chl;
#pragma unroll
      for (int g = 0; g < 4; ++g) e4[g] = ep[g * 4];
    }
    {
      f4v l0hh = {0.f, 0.f, 0.f, 0.f}, l0hl = l0hh, l0lh = l0hh;
      f4v x1hh = l0hh, x1hl = l0hh, x1lh = l0hh;
      f4v h1hh = l0hh, h1hl = l0hh, h1lh = l0hh;
      const short* a0h = H0H[r0] + foff;
      const short* a0l = H0L[r0] + foff;
      const short* a1h = H1H[a] + foff;
      const short* a1l = H1L[a] + foff;
      const short* b0h = &wlds[0 * WROWS + woff];
      const short* b0l = &wlds[1 * WROWS + woff];
      const short* b2h = &wlds[2 * WROWS + woff];
      const short* b2l = &wlds[3 * WROWS + woff];
      const short* b4h = &wlds[4 * WROWS + woff];
      const short* b4l = &wlds[5 * WROWS + woff];
#pragma unroll
      for (int ks = 0; ks < 8; ++ks) {
        s8v A0h = *(const s8v*)(a0h + ks * 32);
        s8v A0l = *(const s8v*)(a0l + ks * 32);
        if (do_l0) {
          s8v B0h = *(const s8v*)(b0h + ks * 32);
          s8v B0l = *(const s8v*)(b0l + ks * 32);
          l0hh = __builtin_amdgcn_mfma_f32_16x16x32_bf16(A0h, B0h, l0hh, 0, 0, 0);
          l0hl = __builtin_amdgcn_mfma_f32_16x16x32_bf16(A0h, B0l, l0hl, 0, 0, 0);
          l0lh = __builtin_amdgcn_mfma_f32_16x16x32_bf16(A0l, B0h, l0lh, 0, 0, 0);
        }
        if (do_l1) {
          s8v B2h = *(const s8v*)(b2h + ks * 32);
          s8v B2l = *(const s8v*)(b2l + ks * 32);
          x1hh = __builtin_amdgcn_mfma_f32_16x16x32_bf16(A0h, B2h, x1hh, 0, 0, 0);
          x1hl = __builtin_amdgcn_mfma_f32_16x16x32_bf16(A0h, B2l, x1hl, 0, 0, 0);
          x1lh = __builtin_amdgcn_mfma_f32_16x16x32_bf16(A0l, B2h, x1lh, 0, 0, 0);
          s8v A1h = *(const s8v*)(a1h + ks * 32);
          s8v A1l = *(const s8v*)(a1l + ks * 32);
          s8v B4h = *(const s8v*)(b4h + ks * 32);
          s8v B4l = *(const s8v*)(b4l + ks * 32);
          h1hh = __builtin_amdgcn_mfma_f32_16x16x32_bf16(A1h, B4h, h1hh, 0, 0, 0);
          h1hl = __builtin_amdgcn_mfma_f32_16x16x32_bf16(A1h, B4l, h1hl, 0, 0, 0);
          h1lh = __builtin_amdgcn_mfma_f32_16x16x32_bf16(A1l, B4h, h1lh, 0, 0, 0);
        }
      }
      if (do_l0) {
        f4v s = l0hh + l0hl + l0lh;
#pragma unroll
        for (int r = 0; r < 4; ++r) gbuf[0][kh][mt * 16 + fq * 4 + r][fr] = s[r];
      }
      if (do_l1) {
        f4v s = x1hh + x1hl + x1lh + h1hh + h1hl + h1lh;
#pragma unroll
        for (int r = 0; r < 4; ++r) gbuf[1][kh][mt * 16 + fq * 4 + r][fr] = s[r];
      }
    }
    __syncthreads();
    if (tid < 128) {
      if (do_l0) {
        float g4[4];
#pragma unroll
        for (int g = 0; g < 4; ++g) {
          int c = g * 4 + chl;
          g4[g] = gbuf[0][0][cb][c] + gbuf[0][1][cb][c] + ctxp_l[cb][c] + e4[g];
        }
        float cn = sigm(g4[1]) * c0r + sigm(g4[0]) * tanhf(g4[2]);
        float hn = sigm(g4[3]) * tanhf(cn);
        c0r = cn;
        short hh = f2bf(hn);
        cstore16(&H0H[a][cb * 512 + hb4 + chl], hh);
        cstore16(&H0L[a][cb * 512 + hb4 + chl], f2bf(hn - bf2f(hh)));
      }
    } else if (do_l1) {
      float g4[4];
#pragma unroll
      for (int g = 0; g < 4; ++g) {
        int c = g * 4 + chl;
        g4[g] = gbuf[1][0][cb][c] + gbuf[1][1][cb][c] + bias1_l[c];
      }
      float cn = sigm(g4[1]) * c1r + sigm(g4[0]) * tanhf(g4[2]);
      float hn = sigm(g4[3]) * tanhf(cn);
      c1r = cn;
      short hh = f2bf(hn);
      cstore16(&H1H[r0][cb * 512 + hb4 + chl], hh);
      cstore16(&H1L[r0][cb * 512 + hb4 + chl], f2bf(hn - bf2f(hh)));
      cstore16(&h1seqbf[((long)cb * 64 + (p - 1)) * 512 + hb4 + chl], hh);
    }
    if (p < 64) {
      asm volatile("s_waitcnt vmcnt(0)" ::: "memory");
      __syncthreads();
      if (tid == 0)
        __hip_atomic_store(&arr[(unsigned)blockIdx.x << 5], (unsigned)(p + 1),
                           __ATOMIC_RELAXED, __HIP_MEMORY_SCOPE_AGENT);
    }
  }
}

extern "C" void kernel_launch(void* const* d_in, const int* in_sizes, int n_in,
                              void* d_out, int out_size, void* d_ws, size_t ws_size,
                              hipStream_t stream) {
  const int*   tokens  = (const int*)  d_in[0];
  const float* enc_out = (const float*)d_in[1];
  const float* enc_h   = (const float*)d_in[2];
  const float* enc_c   = (const float*)d_in[3];
  const float* emb     = (const float*)d_in[4];
  const float* attn1_w = (const float*)d_in[5];
  const float* attn2_w = (const float*)d_in[7];
  const float* w_ih0   = (const float*)d_in[9];
  const float* w_hh0   = (const float*)d_in[10];
  const float* b_ih0   = (const float*)d_in[11];
  const float* b_hh0   = (const float*)d_in[12];
  const float* w_ih1   = (const float*)d_in[13];
  const float* w_hh1   = (const float*)d_in[14];
  const float* b_ih1   = (const float*)d_in[15];
  const float* b_hh1   = (const float*)d_in[16];
  const float* out_w   = (const float*)d_in[17];
  const float* out_b   = (const float*)d_in[18];
  float* out = (float*)d_out;

  float* f = (float*)d_ws;
  float*    w_enc    = f;                        // 1024
  float*    ctx      = f + 1024;                 // 32*1024
  float*    ctxpre   = f + 33792;                // 32*2048
  float*    embp2    = f + 99328;                // 128*64*32*16 = 4M floats
  short*    h1seqbf  = (short*)(f + 4293632);    // 2048*512 shorts
  short*    hbuf     = (short*)(f + 4817920);    // 8 x 16384 shorts
  unsigned* arr      = (unsigned*)(f + 4883456); // 128*32 + pad
  short*    out_w_bf = (short*)(f + 4887616);    // 32000*512 shorts (optional)
  const size_t NEED = (size_t)(4887616 + 8192000) * 4;
  const bool big = ws_size >= NEED;

  k_init2<<<64, 256, 0, stream>>>(enc_h, hbuf, arr);
  k_weff<<<32, 256, 0, stream>>>(attn1_w, attn2_w, w_enc);
  k_attn<<<32, 256, 0, stream>>>(enc_out, w_enc, ctx);
  k_ctxpre<<<256, 256, 0, stream>>>(w_ih0, b_ih0, b_hh0, ctx, ctxpre);
  gemm_bf16<2><<<dim3(16, 16), 256, 0, stream>>>(emb, w_ih0, tokens, nullptr,
                                                 embp2, 512, 512, 1536, 0);
  if (big) k_cvt<<<8000, 256, 0, stream>>>(out_w, out_w_bf);
  lstm_persist<<<NBLK, 256, 0, stream>>>(w_hh0, w_ih1, w_hh1, b_ih1, b_hh1, enc_c,
                                         embp2, ctxpre, hbuf, h1seqbf, arr);
  if (big)
    gemm_out<false><<<dim3(16, 250), 256, 0, stream>>>(h1seqbf, out_w_bf, nullptr,
                                                       out_b, out);
  else
    gemm_out<true><<<dim3(16, 250), 256, 0, stream>>>(h1seqbf, nullptr, out_w,
                                                      out_b, out);
}

// Round 6
// 722.917 us; speedup vs baseline: 7.3857x; 1.4604x over previous
//
#include <hip/hip_runtime.h>
#include <hip/hip_bf16.h>

typedef __attribute__((ext_vector_type(4))) float f4v;
typedef __attribute__((ext_vector_type(4))) short s4v;
typedef __attribute__((ext_vector_type(8))) short s8v;

#define DEVINL __device__ __forceinline__
#define NBLK 128
#define PADK 536          // 512 + 24 shorts padding
#define WROWS (16 * PADK) // shorts per weight slice
#define HSLOT 16384       // shorts per h buffer slot (32 x 512)

DEVINL short f2bf(float f) {
  unsigned u = __float_as_uint(f);
  u += 0x7FFFu + ((u >> 16) & 1u);
  return (short)(u >> 16);
}
DEVINL float bf2f(short s) {
  return __uint_as_float(((unsigned)(unsigned short)s) << 16);
}
DEVINL float sigm(float x) { return 1.f / (1.f + expf(-x)); }

// coherent (write-through past L2) 8-byte store
DEVINL void cstore64(short* p, unsigned long long d) {
  asm volatile("global_store_dwordx2 %0, %1, off sc0 sc1"
               :: "v"(p), "v"(d) : "memory");
}

// ---- init: h0,h1 (bf16 hi/lo) into slot-0 buffers; zero flag words ---------
__global__ __launch_bounds__(256) void k_init2(const float* __restrict__ enc_h,
                                               short* __restrict__ hbuf,
                                               unsigned* __restrict__ arr) {
  int i = blockIdx.x * 256 + threadIdx.x;  // 0..16383
  float h0 = enc_h[i], h1 = enc_h[16384 + i];
  short h0h = f2bf(h0), h1h = f2bf(h1);
  hbuf[i] = h0h;                                  // H0H slot0
  hbuf[(long)65 * HSLOT + i] = f2bf(h0 - bf2f(h0h));   // H0L slot0
  hbuf[(long)130 * HSLOT + i] = h1h;                   // H1H slot0
  hbuf[(long)195 * HSLOT + i] = f2bf(h1 - bf2f(h1h));  // H1L slot0
  if (i < NBLK * 32 + 32) arr[i] = 0u;
}

// ---- w_enc[j] = sum_k attn2_w[k] * attn1_w[k*2048 + j], j<1024 -------------
__global__ __launch_bounds__(256) void k_weff(const float* __restrict__ attn1_w,
                                              const float* __restrict__ attn2_w,
                                              float* __restrict__ w_enc) {
  __shared__ float part[8][32];
  int t = threadIdx.x;
  int jl = t & 31, kp = t >> 5;
  int j = blockIdx.x * 32 + jl;
  float acc = 0.f;
  for (int k = kp * 256; k < kp * 256 + 256; ++k)
    acc += attn2_w[k] * attn1_w[(long)k * 2048 + j];
  part[kp][jl] = acc;
  __syncthreads();
  if (t < 32) {
    float s = 0.f;
    for (int p = 0; p < 8; ++p) s += part[p][t];
    w_enc[blockIdx.x * 32 + t] = s;
  }
}

// ---- per-b: logits -> softmax -> ctx[b, 0:1024] ----------------------------
__global__ __launch_bounds__(256) void k_attn(const float* __restrict__ enc,
                                              const float* __restrict__ w_enc,
                                              float* __restrict__ ctx) {
  __shared__ float red[256];
  __shared__ float wls[128];
  int b = blockIdx.x, t = threadIdx.x;
  int s = t >> 1, half = t & 1;
  const float* e = enc + ((long)b * 128 + s) * 1024 + half * 512;
  const float* wv = w_enc + half * 512;
  float acc = 0.f;
  for (int k = 0; k < 512; k += 4) {
    f4v ev = *(const f4v*)(e + k);
    f4v w4 = *(const f4v*)(wv + k);
    acc += ev[0] * w4[0] + ev[1] * w4[1] + ev[2] * w4[2] + ev[3] * w4[3];
  }
  red[t] = acc;
  __syncthreads();
  if (half == 0) wls[s] = red[t] + red[t + 1];
  __syncthreads();
  red[t] = (t < 128) ? wls[t] : -3.4e38f;
  __syncthreads();
  for (int off = 128; off >= 1; off >>= 1) {
    if (t < off) red[t] = fmaxf(red[t], red[t + off]);
    __syncthreads();
  }
  float mx = red[0];
  __syncthreads();
  if (t < 128) { float ex = expf(wls[t] - mx); wls[t] = ex; red[t] = ex; }
  else red[t] = 0.f;
  __syncthreads();
  for (int off = 128; off >= 1; off >>= 1) {
    if (t < off) red[t] += red[t + off];
    __syncthreads();
  }
  float inv = 1.f / red[0];
  __syncthreads();
  if (t < 128) wls[t] *= inv;
  __syncthreads();
  float a0 = 0.f, a1 = 0.f, a2 = 0.f, a3 = 0.f;
  for (int ss = 0; ss < 128; ++ss) {
    float w = wls[ss];
    const float* er = enc + ((long)b * 128 + ss) * 1024;
    a0 += w * er[t];
    a1 += w * er[t + 256];
    a2 += w * er[t + 512];
    a3 += w * er[t + 768];
  }
  ctx[b * 1024 + t] = a0;
  ctx[b * 1024 + t + 256] = a1;
  ctx[b * 1024 + t + 512] = a2;
  ctx[b * 1024 + t + 768] = a3;
}

// ---- ctxpre[b][j] = ctx[b] . w_ih0[j, 512:1536] + b_ih0[j] + b_hh0[j] ------
__global__ __launch_bounds__(256) void k_ctxpre(const float* __restrict__ w_ih0,
                                                const float* __restrict__ b_ih0,
                                                const float* __restrict__ b_hh0,
                                                const float* __restrict__ ctx,
                                                float* __restrict__ ctxpre) {
  int t = threadIdx.x;
  int j = blockIdx.x * 8 + (t >> 5);
  int b = t & 31;
  float acc = b_ih0[j] + b_hh0[j];
  const float* w = w_ih0 + (long)j * 1536 + 512;
  const float* c = ctx + b * 1024;
  for (int k = 0; k < 1024; k += 4) {
    f4v wv = *(const f4v*)(w + k);
    f4v cv = *(const f4v*)(c + k);
    acc += wv[0] * cv[0] + wv[1] * cv[1] + wv[2] * cv[2] + wv[3] * cv[3];
  }
  ctxpre[b * 2048 + j] = acc;
}

// ---- fp32 out_w -> bf16 -----------------------------------------------------
__global__ __launch_bounds__(256) void k_cvt(const float* __restrict__ src,
                                             short* __restrict__ dst) {
  long i = ((long)blockIdx.x * 256 + threadIdx.x) * 8;
  f4v a = *(const f4v*)(src + i);
  f4v b = *(const f4v*)(src + i + 4);
  s8v o;
  o[0] = f2bf(a[0]); o[1] = f2bf(a[1]); o[2] = f2bf(a[2]); o[3] = f2bf(a[3]);
  o[4] = f2bf(b[0]); o[5] = f2bf(b[1]); o[6] = f2bf(b[2]); o[7] = f2bf(b[3]);
  *(s8v*)(dst + i) = o;
}

// ---- fp32-input bf16 MFMA GEMM (MODE 2: scatter to embp2 packed layout) ----
template <int MODE>
__global__ __launch_bounds__(256) void gemm_bf16(
    const float* __restrict__ A, const float* __restrict__ B,
    const int* __restrict__ a_rows, const float* __restrict__ bias,
    float* __restrict__ C, int K, int lda, int ldb, int ldc) {
  __shared__ short As[128 * 72];
  __shared__ short Bs[128 * 72];
  int n0 = blockIdx.x * 128, m0 = blockIdx.y * 128;
  int t = threadIdx.x;
  int lane = t & 63, w = t >> 6;
  int wm = w & 1, wn = w >> 1;
  f4v acc[4][4];
#pragma unroll
  for (int mi = 0; mi < 4; ++mi)
#pragma unroll
    for (int ni = 0; ni < 4; ++ni) acc[mi][ni] = (f4v){0.f, 0.f, 0.f, 0.f};

  int sr = t >> 1;
  int sh = (t & 1) * 32;
  long arow = a_rows ? (long)a_rows[m0 + sr] : (long)(m0 + sr);
  const float* ap = A + arow * lda + sh;
  const float* bp = B + (long)(n0 + sr) * ldb + sh;
  short* as = &As[sr * 72 + sh];
  short* bs = &Bs[sr * 72 + sh];

  for (int k0 = 0; k0 < K; k0 += 64) {
#pragma unroll
    for (int i = 0; i < 8; ++i) {
      f4v va = *(const f4v*)(ap + k0 + i * 4);
      f4v vb = *(const f4v*)(bp + k0 + i * 4);
      s4v sa, sb;
      sa[0] = f2bf(va[0]); sa[1] = f2bf(va[1]); sa[2] = f2bf(va[2]); sa[3] = f2bf(va[3]);
      sb[0] = f2bf(vb[0]); sb[1] = f2bf(vb[1]); sb[2] = f2bf(vb[2]); sb[3] = f2bf(vb[3]);
      *(s4v*)(as + i * 4) = sa;
      *(s4v*)(bs + i * 4) = sb;
    }
    __syncthreads();
#pragma unroll
    for (int ks = 0; ks < 2; ++ks) {
      s8v af[4], bf[4];
#pragma unroll
      for (int mi = 0; mi < 4; ++mi)
        af[mi] = *(const s8v*)&As[(wm * 64 + mi * 16 + (lane & 15)) * 72 + ks * 32 + (lane >> 4) * 8];
#pragma unroll
      for (int ni = 0; ni < 4; ++ni)
        bf[ni] = *(const s8v*)&Bs[(wn * 64 + ni * 16 + (lane & 15)) * 72 + ks * 32 + (lane >> 4) * 8];
#pragma unroll
      for (int mi = 0; mi < 4; ++mi)
#pragma unroll
        for (int ni = 0; ni < 4; ++ni)
          acc[mi][ni] = __builtin_amdgcn_mfma_f32_16x16x32_bf16(af[mi], bf[ni], acc[mi][ni], 0, 0, 0);
    }
    __syncthreads();
  }
  int fq = lane >> 4, fr = lane & 15;
#pragma unroll
  for (int mi = 0; mi < 4; ++mi)
#pragma unroll
    for (int ni = 0; ni < 4; ++ni) {
      int col = n0 + wn * 64 + ni * 16 + fr;
      long rowb = m0 + wm * 64 + mi * 16 + fq * 4;
      if (MODE == 2) {
        int bz = (col & 511) >> 2;
        int c = ((col >> 9) << 2) + (col & 3);
#pragma unroll
        for (int r = 0; r < 4; ++r) {
          long m = rowb + r;  // = b*64 + t
          C[(long)bz * 32768 + (m & 63) * 512 + (m >> 6) * 16 + c] = acc[mi][ni][r];
        }
      } else {
        float bv = bias ? bias[col] : 0.f;
#pragma unroll
        for (int r = 0; r < 4; ++r) C[(rowb + r) * (long)ldc + col] = acc[mi][ni][r] + bv;
      }
    }
}

// ---- output GEMM: A bf16 [2048][512], B bf16 (or fp32 if BCVT) [32000][512] -
template <bool BCVT>
__global__ __launch_bounds__(256) void gemm_out(
    const short* __restrict__ A, const short* __restrict__ Bbf,
    const float* __restrict__ Bf, const float* __restrict__ bias,
    float* __restrict__ C) {
  __shared__ short As[128 * 72];
  __shared__ short Bs[128 * 72];
  int m0 = blockIdx.x * 128, n0 = blockIdx.y * 128;
  int t = threadIdx.x;
  int lane = t & 63, w = t >> 6;
  int wm = w & 1, wn = w >> 1;
  f4v acc[4][4];
#pragma unroll
  for (int mi = 0; mi < 4; ++mi)
#pragma unroll
    for (int ni = 0; ni < 4; ++ni) acc[mi][ni] = (f4v){0.f, 0.f, 0.f, 0.f};

  int sr = t >> 1;
  int sh = (t & 1) * 32;
  const short* ap = A + (long)(m0 + sr) * 512 + sh;
  const short* bpb = Bbf + (long)(n0 + sr) * 512 + sh;
  const float* bpf = Bf + (long)(n0 + sr) * 512 + sh;
  short* as = &As[sr * 72 + sh];
  short* bs = &Bs[sr * 72 + sh];

  for (int k0 = 0; k0 < 512; k0 += 64) {
#pragma unroll
    for (int i = 0; i < 4; ++i)
      *(s8v*)(as + i * 8) = *(const s8v*)(ap + k0 + i * 8);
    if (BCVT) {
#pragma unroll
      for (int i = 0; i < 8; ++i) {
        f4v vb = *(const f4v*)(bpf + k0 + i * 4);
        s4v sb;
        sb[0] = f2bf(vb[0]); sb[1] = f2bf(vb[1]); sb[2] = f2bf(vb[2]); sb[3] = f2bf(vb[3]);
        *(s4v*)(bs + i * 4) = sb;
      }
    } else {
#pragma unroll
      for (int i = 0; i < 4; ++i)
        *(s8v*)(bs + i * 8) = *(const s8v*)(bpb + k0 + i * 8);
    }
    __syncthreads();
#pragma unroll
    for (int ks = 0; ks < 2; ++ks) {
      s8v af[4], bf[4];
#pragma unroll
      for (int mi = 0; mi < 4; ++mi)
        af[mi] = *(const s8v*)&As[(wm * 64 + mi * 16 + (lane & 15)) * 72 + ks * 32 + (lane >> 4) * 8];
#pragma unroll
      for (int ni = 0; ni < 4; ++ni)
        bf[ni] = *(const s8v*)&Bs[(wn * 64 + ni * 16 + (lane & 15)) * 72 + ks * 32 + (lane >> 4) * 8];
#pragma unroll
      for (int mi = 0; mi < 4; ++mi)
#pragma unroll
        for (int ni = 0; ni < 4; ++ni)
          acc[mi][ni] = __builtin_amdgcn_mfma_f32_16x16x32_bf16(af[mi], bf[ni], acc[mi][ni], 0, 0, 0);
    }
    __syncthreads();
  }
  int fq = lane >> 4, fr = lane & 15;
#pragma unroll
  for (int mi = 0; mi < 4; ++mi)
#pragma unroll
    for (int ni = 0; ni < 4; ++ni) {
      int col = n0 + wn * 64 + ni * 16 + fr;
      float bv = bias[col];
      long rowb = m0 + wm * 64 + mi * 16 + fq * 4;
#pragma unroll
      for (int r = 0; r < 4; ++r)
        __builtin_nontemporal_store(acc[mi][ni][r] + bv, &C[(rowb + r) * 32000L + col]);
    }
}

// ---- persistent fused 2-layer LSTM: 65 phases, rotating h slots -------------
// h state rotates through 65 fresh slots per buffer -> within a launch no
// reader can hold a stale L2 line for a slot (demand-fetched only after the
// producer's write-through + flag). One buffer_inv at kernel start clears any
// lines left from prior dispatches/replays. Readers use plain CACHED loads
// (16 blocks/XCD share one L2 fill). Writers publish packed 8B write-through
// stores, then set a per-block flag (own cache line).
__global__ __launch_bounds__(256, 1) void lstm_persist(
    const float* __restrict__ w_hh0, const float* __restrict__ w_ih1,
    const float* __restrict__ w_hh1,
    const float* __restrict__ b_ih1, const float* __restrict__ b_hh1,
    const float* __restrict__ enc_c,
    const float* __restrict__ embp2, const float* __restrict__ ctxpre,
    short* __restrict__ hbuf, short* __restrict__ h1seqbf,
    unsigned* __restrict__ arr) {
  __shared__ alignas(16) short wlds[6 * WROWS];  // w0 h/l, w1ih h/l, w1hh h/l
  __shared__ float ctxp_l[32][16];
  __shared__ float bias1_l[16];
  __shared__ float gbuf[2][2][32][17];           // [layer][kh][row][col]
  __shared__ float hst[2][32][4];                // cell outputs for packing

  const int tid = threadIdx.x;
  const int hb4 = blockIdx.x * 4;
  const int lane = tid & 63, wid = tid >> 6;
  const int mt = wid & 1, kh = wid >> 1;
  const int fr = lane & 15, fq = lane >> 4;

  // stage weight slices (rows c = gate*4 + hlocal)
  for (int base = tid * 4; base < 48 * 512; base += 1024) {
    int row = base >> 9, k = base & 511;
    int m = row >> 4, c = row & 15;
    int j = ((c >> 2) << 9) + hb4 + (c & 3);
    const float* wsrc = (m == 0) ? w_hh0 : ((m == 1) ? w_ih1 : w_hh1);
    f4v v = *(const f4v*)(wsrc + (long)j * 512 + k);
    short* hi = &wlds[(m * 2) * WROWS + c * PADK + k];
    short* lo = &wlds[(m * 2 + 1) * WROWS + c * PADK + k];
#pragma unroll
    for (int e = 0; e < 4; ++e) {
      short hh = f2bf(v[e]);
      hi[e] = hh;
      lo[e] = f2bf(v[e] - bf2f(hh));
    }
  }
  for (int i = tid; i < 512; i += 256) {
    int b = i >> 4, c = i & 15;
    ctxp_l[b][c] = ctxpre[b * 2048 + ((c >> 2) << 9) + hb4 + (c & 3)];
  }
  if (tid < 16) {
    int j = ((tid >> 2) << 9) + hb4 + (tid & 3);
    bias1_l[tid] = b_ih1[j] + b_hh1[j];
  }
  const int cb = tid & 31, chl = (tid >> 5) & 3;
  float c0r = 0.f, c1r = 0.f;
  if (tid < 128) c0r = enc_c[cb * 512 + hb4 + chl];
  else           c1r = enc_c[16384 + cb * 512 + hb4 + chl];
  __syncthreads();
  // insurance: drop any stale (clean) L2 lines from prior dispatches/replays
  // before the first hbuf slot read. Weights already live in LDS/registers.
  asm volatile("s_waitcnt vmcnt(0)" ::: "memory");
  asm volatile("buffer_inv sc1" ::: "memory");
  __syncthreads();

  short* H0H = hbuf;                       // + slot*HSLOT
  short* H0L = hbuf + (long)65 * HSLOT;
  short* H1H = hbuf + (long)130 * HSLOT;
  short* H1L = hbuf + (long)195 * HSLOT;
  const int foff = (mt * 16 + fr) * 512 + kh * 256 + fq * 8;
  const int woff = fr * PADK + kh * 256 + fq * 8;

  for (int p = 0; p <= 64; ++p) {
    const bool do_l0 = (p < 64), do_l1 = (p > 0);
    if (p) {
      // wait for all blocks to have published phase-p inputs
      if (tid < NBLK)
        while (__hip_atomic_load(&arr[tid << 5], __ATOMIC_RELAXED,
                                 __HIP_MEMORY_SCOPE_AGENT) < (unsigned)p)
          __builtin_amdgcn_s_sleep(1);
      __syncthreads();
    }
    // prefetch embp2 for layer0 step t0=p (contiguous 2KB per block)
    float e4[4] = {0.f, 0.f, 0.f, 0.f};
    if (do_l0 && tid < 128) {
      const float* ep = embp2 + (long)blockIdx.x * 32768 + p * 512 + cb * 16 + chl;
#pragma unroll
      for (int g = 0; g < 4; ++g) e4[g] = ep[g * 4];
    }
    {
      const int pm1 = do_l1 ? (p - 1) : 0;
      f4v l0hh = {0.f, 0.f, 0.f, 0.f}, l0hl = l0hh, l0lh = l0hh;
      f4v x1hh = l0hh, x1hl = l0hh, x1lh = l0hh;
      f4v h1hh = l0hh, h1hl = l0hh, h1lh = l0hh;
      const short* a0h = H0H + (long)p * HSLOT + foff;     // h0 state(p), cached
      const short* a0l = H0L + (long)p * HSLOT + foff;
      const short* a1h = H1H + (long)pm1 * HSLOT + foff;   // h1 state(p-1)
      const short* a1l = H1L + (long)pm1 * HSLOT + foff;
      const short* b0h = &wlds[0 * WROWS + woff];
      const short* b0l = &wlds[1 * WROWS + woff];
      const short* b2h = &wlds[2 * WROWS + woff];
      const short* b2l = &wlds[3 * WROWS + woff];
      const short* b4h = &wlds[4 * WROWS + woff];
      const short* b4l = &wlds[5 * WROWS + woff];
#pragma unroll
      for (int ks = 0; ks < 8; ++ks) {
        s8v A0h = *(const s8v*)(a0h + ks * 32);
        s8v A0l = *(const s8v*)(a0l + ks * 32);
        if (do_l0) {
          s8v B0h = *(const s8v*)(b0h + ks * 32);
          s8v B0l = *(const s8v*)(b0l + ks * 32);
          l0hh = __builtin_amdgcn_mfma_f32_16x16x32_bf16(A0h, B0h, l0hh, 0, 0, 0);
          l0hl = __builtin_amdgcn_mfma_f32_16x16x32_bf16(A0h, B0l, l0hl, 0, 0, 0);
          l0lh = __builtin_amdgcn_mfma_f32_16x16x32_bf16(A0l, B0h, l0lh, 0, 0, 0);
        }
        if (do_l1) {
          s8v B2h = *(const s8v*)(b2h + ks * 32);
          s8v B2l = *(const s8v*)(b2l + ks * 32);
          x1hh = __builtin_amdgcn_mfma_f32_16x16x32_bf16(A0h, B2h, x1hh, 0, 0, 0);
          x1hl = __builtin_amdgcn_mfma_f32_16x16x32_bf16(A0h, B2l, x1hl, 0, 0, 0);
          x1lh = __builtin_amdgcn_mfma_f32_16x16x32_bf16(A0l, B2h, x1lh, 0, 0, 0);
          s8v A1h = *(const s8v*)(a1h + ks * 32);
          s8v A1l = *(const s8v*)(a1l + ks * 32);
          s8v B4h = *(const s8v*)(b4h + ks * 32);
          s8v B4l = *(const s8v*)(b4l + ks * 32);
          h1hh = __builtin_amdgcn_mfma_f32_16x16x32_bf16(A1h, B4h, h1hh, 0, 0, 0);
          h1hl = __builtin_amdgcn_mfma_f32_16x16x32_bf16(A1h, B4l, h1hl, 0, 0, 0);
          h1lh = __builtin_amdgcn_mfma_f32_16x16x32_bf16(A1l, B4h, h1lh, 0, 0, 0);
        }
      }
      if (do_l0) {
        f4v s = l0hh + l0hl + l0lh;
#pragma unroll
        for (int r = 0; r < 4; ++r) gbuf[0][kh][mt * 16 + fq * 4 + r][fr] = s[r];
      }
      if (do_l1) {
        f4v s = x1hh + x1hl + x1lh + h1hh + h1hl + h1lh;
#pragma unroll
        for (int r = 0; r < 4; ++r) gbuf[1][kh][mt * 16 + fq * 4 + r][fr] = s[r];
      }
    }
    __syncthreads();
    // cell updates -> hst (LDS)
    if (tid < 128) {
      if (do_l0) {
        float g4[4];
#pragma unroll
        for (int g = 0; g < 4; ++g) {
          int c = g * 4 + chl;
          g4[g] = gbuf[0][0][cb][c] + gbuf[0][1][cb][c] + ctxp_l[cb][c] + e4[g];
        }
        float cn = sigm(g4[1]) * c0r + sigm(g4[0]) * tanhf(g4[2]);
        float hn = sigm(g4[3]) * tanhf(cn);
        c0r = cn;
        hst[0][cb][chl] = hn;
      }
    } else if (do_l1) {
      float g4[4];
#pragma unroll
      for (int g = 0; g < 4; ++g) {
        int c = g * 4 + chl;
        g4[g] = gbuf[1][0][cb][c] + gbuf[1][1][cb][c] + bias1_l[c];
      }
      float cn = sigm(g4[1]) * c1r + sigm(g4[0]) * tanhf(g4[2]);
      float hn = sigm(g4[3]) * tanhf(cn);
      c1r = cn;
      hst[1][cb][chl] = hn;
    }
    __syncthreads();
    // packed coherent publication: 8B dwordx2 per (batch, buffer)
    if (do_l0 && tid < 32) {
      unsigned long long hiw = 0ull, low = 0ull;
#pragma unroll
      for (int e = 0; e < 4; ++e) {
        float v = hst[0][tid][e];
        short hh = f2bf(v);
        hiw |= (unsigned long long)(unsigned short)hh << (16 * e);
        low |= (unsigned long long)(unsigned short)f2bf(v - bf2f(hh)) << (16 * e);
      }
      cstore64(H0H + (long)(p + 1) * HSLOT + tid * 512 + hb4, hiw);
      cstore64(H0L + (long)(p + 1) * HSLOT + tid * 512 + hb4, low);
    }
    if (do_l1 && tid >= 32 && tid < 64) {
      int cb2 = tid - 32;
      unsigned long long hiw = 0ull, low = 0ull;
#pragma unroll
      for (int e = 0; e < 4; ++e) {
        float v = hst[1][cb2][e];
        short hh = f2bf(v);
        hiw |= (unsigned long long)(unsigned short)hh << (16 * e);
        low |= (unsigned long long)(unsigned short)f2bf(v - bf2f(hh)) << (16 * e);
      }
      cstore64(H1H + (long)p * HSLOT + cb2 * 512 + hb4, hiw);
      cstore64(H1L + (long)p * HSLOT + cb2 * 512 + hb4, low);
      // h1seq output (plain store, consumed after kernel end)
      *(unsigned long long*)&h1seqbf[((long)cb2 * 64 + (p - 1)) * 512 + hb4] = hiw;
    }
    if (p < 64) {
      asm volatile("s_waitcnt vmcnt(0)" ::: "memory");
      __syncthreads();
      if (tid == 0)
        __hip_atomic_store(&arr[(unsigned)blockIdx.x << 5], (unsigned)(p + 1),
                           __ATOMIC_RELAXED, __HIP_MEMORY_SCOPE_AGENT);
    }
  }
}

extern "C" void kernel_launch(void* const* d_in, const int* in_sizes, int n_in,
                              void* d_out, int out_size, void* d_ws, size_t ws_size,
                              hipStream_t stream) {
  const int*   tokens  = (const int*)  d_in[0];
  const float* enc_out = (const float*)d_in[1];
  const float* enc_h   = (const float*)d_in[2];
  const float* enc_c   = (const float*)d_in[3];
  const float* emb     = (const float*)d_in[4];
  const float* attn1_w = (const float*)d_in[5];
  const float* attn2_w = (const float*)d_in[7];
  const float* w_ih0   = (const float*)d_in[9];
  const float* w_hh0   = (const float*)d_in[10];
  const float* b_ih0   = (const float*)d_in[11];
  const float* b_hh0   = (const float*)d_in[12];
  const float* w_ih1   = (const float*)d_in[13];
  const float* w_hh1   = (const float*)d_in[14];
  const float* b_ih1   = (const float*)d_in[15];
  const float* b_hh1   = (const float*)d_in[16];
  const float* out_w   = (const float*)d_in[17];
  const float* out_b   = (const float*)d_in[18];
  float* out = (float*)d_out;

  float* f = (float*)d_ws;
  float*    w_enc    = f;                        // [0, 1024)
  float*    ctx      = f + 1024;                 // [1024, 33792)
  float*    ctxpre   = f + 33792;                // [33792, 99328)
  float*    embp2    = f + 99328;                // [99328, 4293632)
  short*    h1seqbf  = (short*)(f + 4293632);    // 1,048,576 shorts -> [.., 4817920)
  short*    hbuf     = (short*)(f + 4817920);    // 260 x 16384 shorts -> [.., 6947840)
  unsigned* arr      = (unsigned*)(f + 6947840); // 4128 uints -> [.., 6951968)
  short*    out_w_bf = (short*)(f + 6952000);    // 16,384,000 shorts (optional)
  const size_t NEED = (size_t)(6952000 + 8192000) * 4;
  const bool big = ws_size >= NEED;

  k_init2<<<64, 256, 0, stream>>>(enc_h, hbuf, arr);
  k_weff<<<32, 256, 0, stream>>>(attn1_w, attn2_w, w_enc);
  k_attn<<<32, 256, 0, stream>>>(enc_out, w_enc, ctx);
  k_ctxpre<<<256, 256, 0, stream>>>(w_ih0, b_ih0, b_hh0, ctx, ctxpre);
  gemm_bf16<2><<<dim3(16, 16), 256, 0, stream>>>(emb, w_ih0, tokens, nullptr,
                                                 embp2, 512, 512, 1536, 0);
  if (big) k_cvt<<<8000, 256, 0, stream>>>(out_w, out_w_bf);
  lstm_persist<<<NBLK, 256, 0, stream>>>(w_hh0, w_ih1, w_hh1, b_ih1, b_hh1, enc_c,
                                         embp2, ctxpre, hbuf, h1seqbf, arr);
  if (big)
    gemm_out<false><<<dim3(16, 250), 256, 0, stream>>>(h1seqbf, out_w_bf, nullptr,
                                                       out_b, out);
  else
    gemm_out<true><<<dim3(16, 250), 256, 0, stream>>>(h1seqbf, nullptr, out_w,
                                                      out_b, out);
}

// Round 7
// 635.592 us; speedup vs baseline: 8.4004x; 1.1374x over previous
//
#include <hip/hip_runtime.h>
#include <hip/hip_bf16.h>

typedef __attribute__((ext_vector_type(4))) float f4v;
typedef __attribute__((ext_vector_type(4))) short s4v;
typedef __attribute__((ext_vector_type(8))) short s8v;

#define DEVINL __device__ __forceinline__
#define NBLK 128
#define PADK 536          // 512 + 24 shorts padding
#define WROWS (16 * PADK) // shorts per weight slice
#define HSLOT 16384       // shorts per h slot (32 batches x 512 dims, bf16 hi)

DEVINL short f2bf(float f) {
  unsigned u = __float_as_uint(f);
  u += 0x7FFFu + ((u >> 16) & 1u);
  return (short)(u >> 16);
}
DEVINL float bf2f(short s) {
  return __uint_as_float(((unsigned)(unsigned short)s) << 16);
}
DEVINL float sigm(float x) { return 1.f / (1.f + expf(-x)); }

// coherent (write-through past L2) 8-byte store
DEVINL void cstore64(short* p, unsigned long long d) {
  asm volatile("global_store_dwordx2 %0, %1, off sc0 sc1"
               :: "v"(p), "v"(d) : "memory");
}

// ---- init: h0,h1 (bf16) into slot-0 buffers; zero flag words ---------------
__global__ __launch_bounds__(256) void k_init2(const float* __restrict__ enc_h,
                                               short* __restrict__ hbuf,
                                               unsigned* __restrict__ arr) {
  int i = blockIdx.x * 256 + threadIdx.x;  // 0..16383
  hbuf[i] = f2bf(enc_h[i]);                           // H0 slot0
  hbuf[(long)65 * HSLOT + i] = f2bf(enc_h[16384 + i]); // H1 slot0
  if (i < NBLK * 32 + 32) arr[i] = 0u;
}

// ---- w_enc[j] = sum_k attn2_w[k] * attn1_w[k*2048 + j], j<1024 -------------
__global__ __launch_bounds__(256) void k_weff(const float* __restrict__ attn1_w,
                                              const float* __restrict__ attn2_w,
                                              float* __restrict__ w_enc) {
  __shared__ float part[8][32];
  int t = threadIdx.x;
  int jl = t & 31, kp = t >> 5;
  int j = blockIdx.x * 32 + jl;
  float acc = 0.f;
  for (int k = kp * 256; k < kp * 256 + 256; ++k)
    acc += attn2_w[k] * attn1_w[(long)k * 2048 + j];
  part[kp][jl] = acc;
  __syncthreads();
  if (t < 32) {
    float s = 0.f;
    for (int p = 0; p < 8; ++p) s += part[p][t];
    w_enc[blockIdx.x * 32 + t] = s;
  }
}

// ---- per-b: logits -> softmax -> ctx[b, 0:1024] ----------------------------
__global__ __launch_bounds__(256) void k_attn(const float* __restrict__ enc,
                                              const float* __restrict__ w_enc,
                                              float* __restrict__ ctx) {
  __shared__ float red[256];
  __shared__ float wls[128];
  int b = blockIdx.x, t = threadIdx.x;
  int s = t >> 1, half = t & 1;
  const float* e = enc + ((long)b * 128 + s) * 1024 + half * 512;
  const float* wv = w_enc + half * 512;
  float acc = 0.f;
  for (int k = 0; k < 512; k += 4) {
    f4v ev = *(const f4v*)(e + k);
    f4v w4 = *(const f4v*)(wv + k);
    acc += ev[0] * w4[0] + ev[1] * w4[1] + ev[2] * w4[2] + ev[3] * w4[3];
  }
  red[t] = acc;
  __syncthreads();
  if (half == 0) wls[s] = red[t] + red[t + 1];
  __syncthreads();
  red[t] = (t < 128) ? wls[t] : -3.4e38f;
  __syncthreads();
  for (int off = 128; off >= 1; off >>= 1) {
    if (t < off) red[t] = fmaxf(red[t], red[t + off]);
    __syncthreads();
  }
  float mx = red[0];
  __syncthreads();
  if (t < 128) { float ex = expf(wls[t] - mx); wls[t] = ex; red[t] = ex; }
  else red[t] = 0.f;
  __syncthreads();
  for (int off = 128; off >= 1; off >>= 1) {
    if (t < off) red[t] += red[t + off];
    __syncthreads();
  }
  float inv = 1.f / red[0];
  __syncthreads();
  if (t < 128) wls[t] *= inv;
  __syncthreads();
  float a0 = 0.f, a1 = 0.f, a2 = 0.f, a3 = 0.f;
  for (int ss = 0; ss < 128; ++ss) {
    float w = wls[ss];
    const float* er = enc + ((long)b * 128 + ss) * 1024;
    a0 += w * er[t];
    a1 += w * er[t + 256];
    a2 += w * er[t + 512];
    a3 += w * er[t + 768];
  }
  ctx[b * 1024 + t] = a0;
  ctx[b * 1024 + t + 256] = a1;
  ctx[b * 1024 + t + 512] = a2;
  ctx[b * 1024 + t + 768] = a3;
}

// ---- ctxpre[b][j] = ctx[b] . w_ih0[j, 512:1536] + b_ih0[j] + b_hh0[j] ------
__global__ __launch_bounds__(256) void k_ctxpre(const float* __restrict__ w_ih0,
                                                const float* __restrict__ b_ih0,
                                                const float* __restrict__ b_hh0,
                                                const float* __restrict__ ctx,
                                                float* __restrict__ ctxpre) {
  int t = threadIdx.x;
  int j = blockIdx.x * 8 + (t >> 5);
  int b = t & 31;
  float acc = b_ih0[j] + b_hh0[j];
  const float* w = w_ih0 + (long)j * 1536 + 512;
  const float* c = ctx + b * 1024;
  for (int k = 0; k < 1024; k += 4) {
    f4v wv = *(const f4v*)(w + k);
    f4v cv = *(const f4v*)(c + k);
    acc += wv[0] * cv[0] + wv[1] * cv[1] + wv[2] * cv[2] + wv[3] * cv[3];
  }
  ctxpre[b * 2048 + j] = acc;
}

// ---- fp32 out_w -> bf16 -----------------------------------------------------
__global__ __launch_bounds__(256) void k_cvt(const float* __restrict__ src,
                                             short* __restrict__ dst) {
  long i = ((long)blockIdx.x * 256 + threadIdx.x) * 8;
  f4v a = *(const f4v*)(src + i);
  f4v b = *(const f4v*)(src + i + 4);
  s8v o;
  o[0] = f2bf(a[0]); o[1] = f2bf(a[1]); o[2] = f2bf(a[2]); o[3] = f2bf(a[3]);
  o[4] = f2bf(b[0]); o[5] = f2bf(b[1]); o[6] = f2bf(b[2]); o[7] = f2bf(b[3]);
  *(s8v*)(dst + i) = o;
}

// ---- fp32-input bf16 MFMA GEMM (MODE 2: scatter to embp2 packed layout) ----
template <int MODE>
__global__ __launch_bounds__(256) void gemm_bf16(
    const float* __restrict__ A, const float* __restrict__ B,
    const int* __restrict__ a_rows, const float* __restrict__ bias,
    float* __restrict__ C, int K, int lda, int ldb, int ldc) {
  __shared__ short As[128 * 72];
  __shared__ short Bs[128 * 72];
  int n0 = blockIdx.x * 128, m0 = blockIdx.y * 128;
  int t = threadIdx.x;
  int lane = t & 63, w = t >> 6;
  int wm = w & 1, wn = w >> 1;
  f4v acc[4][4];
#pragma unroll
  for (int mi = 0; mi < 4; ++mi)
#pragma unroll
    for (int ni = 0; ni < 4; ++ni) acc[mi][ni] = (f4v){0.f, 0.f, 0.f, 0.f};

  int sr = t >> 1;
  int sh = (t & 1) * 32;
  long arow = a_rows ? (long)a_rows[m0 + sr] : (long)(m0 + sr);
  const float* ap = A + arow * lda + sh;
  const float* bp = B + (long)(n0 + sr) * ldb + sh;
  short* as = &As[sr * 72 + sh];
  short* bs = &Bs[sr * 72 + sh];

  for (int k0 = 0; k0 < K; k0 += 64) {
#pragma unroll
    for (int i = 0; i < 8; ++i) {
      f4v va = *(const f4v*)(ap + k0 + i * 4);
      f4v vb = *(const f4v*)(bp + k0 + i * 4);
      s4v sa, sb;
      sa[0] = f2bf(va[0]); sa[1] = f2bf(va[1]); sa[2] = f2bf(va[2]); sa[3] = f2bf(va[3]);
      sb[0] = f2bf(vb[0]); sb[1] = f2bf(vb[1]); sb[2] = f2bf(vb[2]); sb[3] = f2bf(vb[3]);
      *(s4v*)(as + i * 4) = sa;
      *(s4v*)(bs + i * 4) = sb;
    }
    __syncthreads();
#pragma unroll
    for (int ks = 0; ks < 2; ++ks) {
      s8v af[4], bf[4];
#pragma unroll
      for (int mi = 0; mi < 4; ++mi)
        af[mi] = *(const s8v*)&As[(wm * 64 + mi * 16 + (lane & 15)) * 72 + ks * 32 + (lane >> 4) * 8];
#pragma unroll
      for (int ni = 0; ni < 4; ++ni)
        bf[ni] = *(const s8v*)&Bs[(wn * 64 + ni * 16 + (lane & 15)) * 72 + ks * 32 + (lane >> 4) * 8];
#pragma unroll
      for (int mi = 0; mi < 4; ++mi)
#pragma unroll
        for (int ni = 0; ni < 4; ++ni)
          acc[mi][ni] = __builtin_amdgcn_mfma_f32_16x16x32_bf16(af[mi], bf[ni], acc[mi][ni], 0, 0, 0);
    }
    __syncthreads();
  }
  int fq = lane >> 4, fr = lane & 15;
#pragma unroll
  for (int mi = 0; mi < 4; ++mi)
#pragma unroll
    for (int ni = 0; ni < 4; ++ni) {
      int col = n0 + wn * 64 + ni * 16 + fr;
      long rowb = m0 + wm * 64 + mi * 16 + fq * 4;
      if (MODE == 2) {
        int bz = (col & 511) >> 2;
        int c = ((col >> 9) << 2) + (col & 3);
#pragma unroll
        for (int r = 0; r < 4; ++r) {
          long m = rowb + r;  // = b*64 + t
          C[(long)bz * 32768 + (m & 63) * 512 + (m >> 6) * 16 + c] = acc[mi][ni][r];
        }
      } else {
        float bv = bias ? bias[col] : 0.f;
#pragma unroll
        for (int r = 0; r < 4; ++r) C[(rowb + r) * (long)ldc + col] = acc[mi][ni][r] + bv;
      }
    }
}

// ---- output GEMM: A bf16 [2048][512], B bf16 (or fp32 if BCVT) [32000][512] -
template <bool BCVT>
__global__ __launch_bounds__(256) void gemm_out(
    const short* __restrict__ A, const short* __restrict__ Bbf,
    const float* __restrict__ Bf, const float* __restrict__ bias,
    float* __restrict__ C) {
  __shared__ short As[128 * 72];
  __shared__ short Bs[128 * 72];
  int m0 = blockIdx.x * 128, n0 = blockIdx.y * 128;
  int t = threadIdx.x;
  int lane = t & 63, w = t >> 6;
  int wm = w & 1, wn = w >> 1;
  f4v acc[4][4];
#pragma unroll
  for (int mi = 0; mi < 4; ++mi)
#pragma unroll
    for (int ni = 0; ni < 4; ++ni) acc[mi][ni] = (f4v){0.f, 0.f, 0.f, 0.f};

  int sr = t >> 1;
  int sh = (t & 1) * 32;
  const short* ap = A + (long)(m0 + sr) * 512 + sh;
  const short* bpb = Bbf + (long)(n0 + sr) * 512 + sh;
  const float* bpf = Bf + (long)(n0 + sr) * 512 + sh;
  short* as = &As[sr * 72 + sh];
  short* bs = &Bs[sr * 72 + sh];

  for (int k0 = 0; k0 < 512; k0 += 64) {
#pragma unroll
    for (int i = 0; i < 4; ++i)
      *(s8v*)(as + i * 8) = *(const s8v*)(ap + k0 + i * 8);
    if (BCVT) {
#pragma unroll
      for (int i = 0; i < 8; ++i) {
        f4v vb = *(const f4v*)(bpf + k0 + i * 4);
        s4v sb;
        sb[0] = f2bf(vb[0]); sb[1] = f2bf(vb[1]); sb[2] = f2bf(vb[2]); sb[3] = f2bf(vb[3]);
        *(s4v*)(bs + i * 4) = sb;
      }
    } else {
#pragma unroll
      for (int i = 0; i < 4; ++i)
        *(s8v*)(bs + i * 8) = *(const s8v*)(bpb + k0 + i * 8);
    }
    __syncthreads();
#pragma unroll
    for (int ks = 0; ks < 2; ++ks) {
      s8v af[4], bf[4];
#pragma unroll
      for (int mi = 0; mi < 4; ++mi)
        af[mi] = *(const s8v*)&As[(wm * 64 + mi * 16 + (lane & 15)) * 72 + ks * 32 + (lane >> 4) * 8];
#pragma unroll
      for (int ni = 0; ni < 4; ++ni)
        bf[ni] = *(const s8v*)&Bs[(wn * 64 + ni * 16 + (lane & 15)) * 72 + ks * 32 + (lane >> 4) * 8];
#pragma unroll
      for (int mi = 0; mi < 4; ++mi)
#pragma unroll
        for (int ni = 0; ni < 4; ++ni)
          acc[mi][ni] = __builtin_amdgcn_mfma_f32_16x16x32_bf16(af[mi], bf[ni], acc[mi][ni], 0, 0, 0);
    }
    __syncthreads();
  }
  int fq = lane >> 4, fr = lane & 15;
#pragma unroll
  for (int mi = 0; mi < 4; ++mi)
#pragma unroll
    for (int ni = 0; ni < 4; ++ni) {
      int col = n0 + wn * 64 + ni * 16 + fr;
      float bv = bias[col];
      long rowb = m0 + wm * 64 + mi * 16 + fq * 4;
#pragma unroll
      for (int r = 0; r < 4; ++r)
        __builtin_nontemporal_store(acc[mi][ni][r] + bv, &C[(rowb + r) * 32000L + col]);
    }
}

// ---- persistent fused 2-layer LSTM: 65 phases, rotating bf16 h slots --------
// h exchanged as pure bf16 (W keeps hi/lo correction in LDS; c-state fp32 in
// regs). Rotating slots -> plain cached reads (L2-shared per XCD), packed 8B
// write-through publish via in-register shfl packing, per-block flag lines.
__global__ __launch_bounds__(256, 1) void lstm_persist(
    const float* __restrict__ w_hh0, const float* __restrict__ w_ih1,
    const float* __restrict__ w_hh1,
    const float* __restrict__ b_ih1, const float* __restrict__ b_hh1,
    const float* __restrict__ enc_c,
    const float* __restrict__ embp2, const float* __restrict__ ctxpre,
    short* __restrict__ hbuf, short* __restrict__ h1seqbf,
    unsigned* __restrict__ arr) {
  __shared__ alignas(16) short wlds[6 * WROWS];  // w0 h/l, w1ih h/l, w1hh h/l
  __shared__ float ctxp_l[32][16];
  __shared__ float bias1_l[16];
  __shared__ float gbuf[2][2][32][17];           // [layer][kh][batch][gatecol]

  const int tid = threadIdx.x;
  const int hb4 = blockIdx.x * 4;
  const int lane = tid & 63, wid = tid >> 6;
  const int mt = wid & 1, kh = wid >> 1;
  const int fr = lane & 15, fq = lane >> 4;

  // stage weight slices (rows c = gate*4 + hlocal), bf16 hi/lo
  for (int base = tid * 4; base < 48 * 512; base += 1024) {
    int row = base >> 9, k = base & 511;
    int m = row >> 4, c = row & 15;
    int j = ((c >> 2) << 9) + hb4 + (c & 3);
    const float* wsrc = (m == 0) ? w_hh0 : ((m == 1) ? w_ih1 : w_hh1);
    f4v v = *(const f4v*)(wsrc + (long)j * 512 + k);
    short* hi = &wlds[(m * 2) * WROWS + c * PADK + k];
    short* lo = &wlds[(m * 2 + 1) * WROWS + c * PADK + k];
#pragma unroll
    for (int e = 0; e < 4; ++e) {
      short hh = f2bf(v[e]);
      hi[e] = hh;
      lo[e] = f2bf(v[e] - bf2f(hh));
    }
  }
  for (int i = tid; i < 512; i += 256) {
    int b = i >> 4, c = i & 15;
    ctxp_l[b][c] = ctxpre[b * 2048 + ((c >> 2) << 9) + hb4 + (c & 3)];
  }
  if (tid < 16) {
    int j = ((tid >> 2) << 9) + hb4 + (tid & 3);
    bias1_l[tid] = b_ih1[j] + b_hh1[j];
  }
  // cell-thread mapping: tid<128 -> layer0, tid>=128 -> layer1;
  // cq = batch, cr = local h dim (0..3); 4-lane groups pack one batch's 4 dims.
  const int cq = (tid & 127) >> 2, cr = tid & 3;
  float c0r = 0.f, c1r = 0.f;
  if (tid < 128) c0r = enc_c[cq * 512 + hb4 + cr];
  else           c1r = enc_c[16384 + cq * 512 + hb4 + cr];
  __syncthreads();
  // insurance: drop stale clean L2 lines from prior dispatches/replays
  asm volatile("s_waitcnt vmcnt(0)" ::: "memory");
  asm volatile("buffer_inv sc1" ::: "memory");
  __syncthreads();

  short* H0 = hbuf;                        // + slot*HSLOT
  short* H1 = hbuf + (long)65 * HSLOT;
  const int foff = (mt * 16 + fr) * 512 + kh * 256 + fq * 8;
  const int woff = fr * PADK + kh * 256 + fq * 8;

  for (int p = 0; p <= 64; ++p) {
    const bool do_l0 = (p < 64), do_l1 = (p > 0);
    if (p) {
      if (tid < NBLK)
        while (__hip_atomic_load(&arr[tid << 5], __ATOMIC_RELAXED,
                                 __HIP_MEMORY_SCOPE_AGENT) < (unsigned)p)
          __builtin_amdgcn_s_sleep(2);
      __syncthreads();
    }
    // prefetch embp2 for layer0 step p (contiguous 2KB per block)
    float e4[4] = {0.f, 0.f, 0.f, 0.f};
    if (do_l0 && tid < 128) {
      const float* ep = embp2 + (long)blockIdx.x * 32768 + p * 512 + cq * 16 + cr;
#pragma unroll
      for (int g = 0; g < 4; ++g) e4[g] = ep[g * 4];
    }
    {
      f4v l0h = {0.f, 0.f, 0.f, 0.f}, l0l = l0h;
      f4v x1h = l0h, x1l = l0h, h1h = l0h, h1l = l0h;
      const short* a0 = H0 + (long)p * HSLOT + foff;                 // h0(p)
      const short* a1 = H1 + (long)(do_l1 ? p - 1 : 0) * HSLOT + foff; // h1(p-1)
      const short* b0h = &wlds[0 * WROWS + woff];
      const short* b0l = &wlds[1 * WROWS + woff];
      const short* b2h = &wlds[2 * WROWS + woff];
      const short* b2l = &wlds[3 * WROWS + woff];
      const short* b4h = &wlds[4 * WROWS + woff];
      const short* b4l = &wlds[5 * WROWS + woff];
#pragma unroll
      for (int ks = 0; ks < 8; ++ks) {
        s8v A0 = *(const s8v*)(a0 + ks * 32);
        if (do_l0) {
          s8v B0h = *(const s8v*)(b0h + ks * 32);
          s8v B0l = *(const s8v*)(b0l + ks * 32);
          l0h = __builtin_amdgcn_mfma_f32_16x16x32_bf16(A0, B0h, l0h, 0, 0, 0);
          l0l = __builtin_amdgcn_mfma_f32_16x16x32_bf16(A0, B0l, l0l, 0, 0, 0);
        }
        if (do_l1) {
          s8v B2h = *(const s8v*)(b2h + ks * 32);
          s8v B2l = *(const s8v*)(b2l + ks * 32);
          x1h = __builtin_amdgcn_mfma_f32_16x16x32_bf16(A0, B2h, x1h, 0, 0, 0);
          x1l = __builtin_amdgcn_mfma_f32_16x16x32_bf16(A0, B2l, x1l, 0, 0, 0);
          s8v A1 = *(const s8v*)(a1 + ks * 32);
          s8v B4h = *(const s8v*)(b4h + ks * 32);
          s8v B4l = *(const s8v*)(b4l + ks * 32);
          h1h = __builtin_amdgcn_mfma_f32_16x16x32_bf16(A1, B4h, h1h, 0, 0, 0);
          h1l = __builtin_amdgcn_mfma_f32_16x16x32_bf16(A1, B4l, h1l, 0, 0, 0);
        }
      }
      if (do_l0) {
        f4v s = l0h + l0l;
#pragma unroll
        for (int r = 0; r < 4; ++r) gbuf[0][kh][mt * 16 + fq * 4 + r][fr] = s[r];
      }
      if (do_l1) {
        f4v s = x1h + x1l + h1h + h1l;
#pragma unroll
        for (int r = 0; r < 4; ++r) gbuf[1][kh][mt * 16 + fq * 4 + r][fr] = s[r];
      }
    }
    __syncthreads();
    // cells + packed publish (4-lane shfl packing, one 8B wt-store per batch)
    if (tid < 128) {
      if (do_l0) {
        float g4[4];
#pragma unroll
        for (int g = 0; g < 4; ++g) {
          int c = g * 4 + cr;
          g4[g] = gbuf[0][0][cq][c] + gbuf[0][1][cq][c] + ctxp_l[cq][c] + e4[g];
        }
        float cn = sigm(g4[1]) * c0r + sigm(g4[0]) * tanhf(g4[2]);
        float hn = sigm(g4[3]) * tanhf(cn);
        c0r = cn;
        unsigned v16 = (unsigned)(unsigned short)f2bf(hn);
        unsigned p01 = v16 | ((unsigned)__shfl_down((int)v16, 1) << 16);
        unsigned long long wd = (unsigned long long)p01 |
            ((unsigned long long)(unsigned)__shfl_down((int)p01, 2) << 32);
        if ((tid & 3) == 0)
          cstore64(H0 + (long)(p + 1) * HSLOT + cq * 512 + hb4, wd);
      }
    } else if (do_l1) {
      float g4[4];
#pragma unroll
      for (int g = 0; g < 4; ++g) {
        int c = g * 4 + cr;
        g4[g] = gbuf[1][0][cq][c] + gbuf[1][1][cq][c] + bias1_l[c];
      }
      float cn = sigm(g4[1]) * c1r + sigm(g4[0]) * tanhf(g4[2]);
      float hn = sigm(g4[3]) * tanhf(cn);
      c1r = cn;
      unsigned v16 = (unsigned)(unsigned short)f2bf(hn);
      unsigned p01 = v16 | ((unsigned)__shfl_down((int)v16, 1) << 16);
      unsigned long long wd = (unsigned long long)p01 |
          ((unsigned long long)(unsigned)__shfl_down((int)p01, 2) << 32);
      if ((tid & 3) == 0) {
        if (p < 64)  // slot 64 is never read (h1seq carries step 63)
          cstore64(H1 + (long)p * HSLOT + cq * 512 + hb4, wd);
        *(unsigned long long*)&h1seqbf[((long)cq * 64 + (p - 1)) * 512 + hb4] = wd;
      }
    }
    if (p < 64) {
      asm volatile("s_waitcnt vmcnt(0)" ::: "memory");
      __syncthreads();
      if (tid == 0)
        __hip_atomic_store(&arr[(unsigned)blockIdx.x << 5], (unsigned)(p + 1),
                           __ATOMIC_RELAXED, __HIP_MEMORY_SCOPE_AGENT);
    }
  }
}

extern "C" void kernel_launch(void* const* d_in, const int* in_sizes, int n_in,
                              void* d_out, int out_size, void* d_ws, size_t ws_size,
                              hipStream_t stream) {
  const int*   tokens  = (const int*)  d_in[0];
  const float* enc_out = (const float*)d_in[1];
  const float* enc_h   = (const float*)d_in[2];
  const float* enc_c   = (const float*)d_in[3];
  const float* emb     = (const float*)d_in[4];
  const float* attn1_w = (const float*)d_in[5];
  const float* attn2_w = (const float*)d_in[7];
  const float* w_ih0   = (const float*)d_in[9];
  const float* w_hh0   = (const float*)d_in[10];
  const float* b_ih0   = (const float*)d_in[11];
  const float* b_hh0   = (const float*)d_in[12];
  const float* w_ih1   = (const float*)d_in[13];
  const float* w_hh1   = (const float*)d_in[14];
  const float* b_ih1   = (const float*)d_in[15];
  const float* b_hh1   = (const float*)d_in[16];
  const float* out_w   = (const float*)d_in[17];
  const float* out_b   = (const float*)d_in[18];
  float* out = (float*)d_out;

  float* f = (float*)d_ws;
  float*    w_enc    = f;                        // [0, 1024)
  float*    ctx      = f + 1024;                 // [1024, 33792)
  float*    ctxpre   = f + 33792;                // [33792, 99328)
  float*    embp2    = f + 99328;                // [99328, 4293632)
  short*    h1seqbf  = (short*)(f + 4293632);    // 1,048,576 shorts -> 4817920
  short*    hbuf     = (short*)(f + 4817920);    // 130 x 16384 shorts -> 5882880
  unsigned* arr      = (unsigned*)(f + 5882880); // 4128 uints -> 5887008
  short*    out_w_bf = (short*)(f + 5887040);    // 16,384,000 shorts (optional)
  const size_t NEED = (size_t)(5887040 + 8192000) * 4;
  const bool big = ws_size >= NEED;

  k_init2<<<64, 256, 0, stream>>>(enc_h, hbuf, arr);
  k_weff<<<32, 256, 0, stream>>>(attn1_w, attn2_w, w_enc);
  k_attn<<<32, 256, 0, stream>>>(enc_out, w_enc, ctx);
  k_ctxpre<<<256, 256, 0, stream>>>(w_ih0, b_ih0, b_hh0, ctx, ctxpre);
  gemm_bf16<2><<<dim3(16, 16), 256, 0, stream>>>(emb, w_ih0, tokens, nullptr,
                                                 embp2, 512, 512, 1536, 0);
  if (big) k_cvt<<<8000, 256, 0, stream>>>(out_w, out_w_bf);
  lstm_persist<<<NBLK, 256, 0, stream>>>(w_hh0, w_ih1, w_hh1, b_ih1, b_hh1, enc_c,
                                         embp2, ctxpre, hbuf, h1seqbf, arr);
  if (big)
    gemm_out<false><<<dim3(16, 250), 256, 0, stream>>>(h1seqbf, out_w_bf, nullptr,
                                                       out_b, out);
  else
    gemm_out<true><<<dim3(16, 250), 256, 0, stream>>>(h1seqbf, nullptr, out_w,
                                                      out_b, out);
}